// Round 9
// baseline (579.030 us; speedup 1.0000x reference)
//
#include <hip/hip_runtime.h>
#include <cstdint>
#include <cstddef>

typedef __bf16 bf16;
typedef __bf16 bf16x4 __attribute__((ext_vector_type(4)));
typedef __bf16 bf16x8 __attribute__((ext_vector_type(8)));
typedef float  f32x4  __attribute__((ext_vector_type(4)));

#define INVF_C 0.20762050593046014f   // log2(10000)/64

// global -> LDS async copy, 16B per lane. LDS base must be wave-uniform;
// HW scatters lane i at base + 16*i. (m97-verified pattern.)
__device__ __forceinline__ void async_copy16(const void* g, void* l)
{
    auto gp = (__attribute__((address_space(1))) const void*)(reinterpret_cast<uintptr_t>(g));
    auto lp = (__attribute__((address_space(3))) void*)(uint32_t)(reinterpret_cast<uintptr_t>(l));
    __builtin_amdgcn_global_load_lds(gp, lp, 16, 0, 0);
}

// ---------------------------------------------------------------------------
// elementwise fp32 -> bf16 cast, 4 elems/thread, n % 4 == 0
// ---------------------------------------------------------------------------
__global__ void cast_to_bf16(const float* __restrict__ in, bf16* __restrict__ out, int n)
{
    const int i = (blockIdx.x * 256 + threadIdx.x) * 4;
    if (i < n) {
        const float4 v = *(const float4*)(in + i);
        out[i]     = (bf16)v.x;
        out[i + 1] = (bf16)v.y;
        out[i + 2] = (bf16)v.z;
        out[i + 3] = (bf16)v.w;
    }
}

// ---------------------------------------------------------------------------
// fused transpose + cast: out[c*R + r] = (bf16)in[r*C + c]; in is RxC fp32.
// grid (C/32, R/32), block (32,8).
// ---------------------------------------------------------------------------
__global__ void transpose_cast(const float* __restrict__ in, bf16* __restrict__ out,
                               int R, int Ccols)
{
    __shared__ float tile[32][33];
    const int c0 = blockIdx.x * 32;
    const int r0 = blockIdx.y * 32;
    const int tx = threadIdx.x, ty = threadIdx.y;
    for (int i = ty; i < 32; i += 8)
        tile[i][tx] = in[(size_t)(r0 + i) * Ccols + c0 + tx];
    __syncthreads();
    for (int i = ty; i < 32; i += 8)
        out[(size_t)(c0 + i) * R + r0 + tx] = (bf16)tile[tx][i];
}

// ---------------------------------------------------------------------------
// transpose_cast for the 3 stacked batch1 weights -> WtAll (4096 x 2048).
// Sections by global col c: [0,512)=W_DKV(2048x512), [512,2560)=W_KR
// (2048x2048), [2560,4096)=W_DQ(2048x1536). grid (128, 64), block (32,8).
// ---------------------------------------------------------------------------
__global__ void transpose_cast3(const float* __restrict__ w0,
                                const float* __restrict__ w1,
                                const float* __restrict__ w2,
                                bf16* __restrict__ outAll)
{
    __shared__ float tile[32][33];
    const int cg0 = blockIdx.x * 32;
    const int r0  = blockIdx.y * 32;
    const float* in; int cl0, Cc;
    if (cg0 < 512)       { in = w0; cl0 = cg0;        Cc = 512;  }
    else if (cg0 < 2560) { in = w1; cl0 = cg0 - 512;  Cc = 2048; }
    else                 { in = w2; cl0 = cg0 - 2560; Cc = 1536; }
    const int tx = threadIdx.x, ty = threadIdx.y;
    for (int i = ty; i < 32; i += 8)
        tile[i][tx] = in[(size_t)(r0 + i) * Cc + cl0 + tx];
    __syncthreads();
    for (int i = ty; i < 32; i += 8)
        outAll[(size_t)(cg0 + i) * 2048 + r0 + tx] = (bf16)tile[tx][i];
}

// ---------------------------------------------------------------------------
// transpose_cast for UK|UV stacked -> Wt45 (4096 x 512). Both (512, 2048).
// grid (128, 16), block (32,8). c<2048 -> UK, else UV.
// ---------------------------------------------------------------------------
__global__ void transpose_cast2(const float* __restrict__ w0,
                                const float* __restrict__ w1,
                                bf16* __restrict__ outAll)
{
    __shared__ float tile[32][33];
    const int cg0 = blockIdx.x * 32;
    const int r0  = blockIdx.y * 32;
    const float* in = (cg0 < 2048) ? w0 : w1;
    const int cl0 = cg0 & 2047;
    const int tx = threadIdx.x, ty = threadIdx.y;
    for (int i = ty; i < 32; i += 8)
        tile[i][tx] = in[(size_t)(r0 + i) * 2048 + cl0 + tx];
    __syncthreads();
    for (int i = ty; i < 32; i += 8)
        outAll[(size_t)(cg0 + i) * 512 + r0 + tx] = (bf16)tile[tx][i];
}

// ---------------------------------------------------------------------------
// Shared GEMM main loop (m97 structure): 128x128 tile, BK=64, 4 waves 2x2,
// global_load_lds width-16 staging into unpadded LDS. Verified rounds 0-8.
// ---------------------------------------------------------------------------
__device__ __forceinline__ void gemm_core(const bf16* __restrict__ A,
                                          const bf16* __restrict__ Bt,
                                          int K, int m0, int n0,
                                          bf16* As, bf16* Bs,
                                          f32x4 (&acc)[4][4])
{
    const int tid  = threadIdx.x;
    const int wave = tid >> 6;
    const int lane = tid & 63;
    const int quad = lane >> 4;
    const int l15  = lane & 15;
    const int wm   = (wave >> 1) * 64;
    const int wn   = (wave & 1) * 64;

    const int srow = lane >> 3;
    const int scol = (lane & 7) * 8;
    const bf16* Ab = A  + (size_t)(m0 + wave * 32 + srow) * K + scol;
    const bf16* Bb = Bt + (size_t)(n0 + wave * 32 + srow) * K + scol;
    bf16* AsW = &As[(wave * 32) * 64];
    bf16* BsW = &Bs[(wave * 32) * 64];

    for (int k0 = 0; k0 < K; k0 += 64) {
        __syncthreads();   // previous tile fully consumed
#pragma unroll
        for (int i = 0; i < 4; ++i) {
            async_copy16(Ab + (size_t)(i * 8) * K + k0, AsW + i * 8 * 64);
            async_copy16(Bb + (size_t)(i * 8) * K + k0, BsW + i * 8 * 64);
        }
        __syncthreads();   // drains vmcnt(0) -> staged data visible
#pragma unroll
        for (int ks = 0; ks < 2; ++ks) {
            bf16x8 af[4], bfr[4];
#pragma unroll
            for (int i = 0; i < 4; ++i)
                af[i] = *(const bf16x8*)&As[(wm + i * 16 + l15) * 64 + ks * 32 + quad * 8];
#pragma unroll
            for (int j = 0; j < 4; ++j)
                bfr[j] = *(const bf16x8*)&Bs[(wn + j * 16 + l15) * 64 + ks * 32 + quad * 8];
#pragma unroll
            for (int i = 0; i < 4; ++i)
#pragma unroll
                for (int j = 0; j < 4; ++j)
                    acc[i][j] = __builtin_amdgcn_mfma_f32_16x16x32_bf16(af[i], bfr[j], acc[i][j], 0, 0, 0);
        }
    }
}

// ---------------------------------------------------------------------------
// Generic C[M,N] = A @ Bt^T + bias; dual fp32/bf16 epilogue (final GEMM).
// ---------------------------------------------------------------------------
__global__ __launch_bounds__(256, 2)
void gemm_bt(const bf16* __restrict__ A, const bf16* __restrict__ Bt,
             const float* __restrict__ bias, float* __restrict__ C,
             bf16* __restrict__ Cb, int M, int N, int K)
{
    __shared__ bf16 As[128 * 64];
    __shared__ bf16 Bs[128 * 64];
    const int m0 = blockIdx.y * 128;
    const int n0 = blockIdx.x * 128;
    f32x4 acc[4][4] = {};
    gemm_core(A, Bt, K, m0, n0, As, Bs, acc);

    const int tid  = threadIdx.x;
    const int wave = tid >> 6;
    const int lane = tid & 63;
    const int quad = lane >> 4;
    const int l15  = lane & 15;
    const int wm   = (wave >> 1) * 64;
    const int wn   = (wave & 1) * 64;

    // C/D layout: col = lane&15, row = quad*4 + r (verified m89/m91)
#pragma unroll
    for (int j = 0; j < 4; ++j) {
        const int col = n0 + wn + j * 16 + l15;
        const float bv = bias[col];
#pragma unroll
        for (int i = 0; i < 4; ++i) {
            const int row = m0 + wm + i * 16 + quad * 4;
#pragma unroll
            for (int r = 0; r < 4; ++r) {
                const float v = acc[i][j][r] + bv;
                if (C)  C [(size_t)(row + r) * N + col] = v;
                if (Cb) Cb[(size_t)(row + r) * N + col] = (bf16)v;
            }
        }
    }
}

// ---------------------------------------------------------------------------
// Batched GEMM #1: A=hb (4096x2048), B=WtAll (4096x2048). N=4096.
// Epilogues: [0,512) -> cKV fp32+bf16; [512,2560) -> krc fp32 AND kR bf16
// (fused RoPE); [2560,4096) -> cQ bf16.
// ---------------------------------------------------------------------------
__global__ __launch_bounds__(256, 2)
void gemm_batch1(const bf16* __restrict__ A, const bf16* __restrict__ WtAll,
                 const float* __restrict__ bDKV, const float* __restrict__ bKR,
                 const float* __restrict__ bDQ,
                 float* __restrict__ cKV_f, bf16* __restrict__ cKVb,
                 float* __restrict__ krc_f, bf16* __restrict__ kR,
                 bf16* __restrict__ cQ)
{
    __shared__ bf16 As[128 * 64];
    __shared__ bf16 Bs[128 * 64];
    const int m0 = blockIdx.y * 128;
    const int n0 = blockIdx.x * 128;
    f32x4 acc[4][4] = {};
    gemm_core(A, WtAll, 2048, m0, n0, As, Bs, acc);

    const int tid  = threadIdx.x;
    const int wave = tid >> 6;
    const int lane = tid & 63;
    const int quad = lane >> 4;
    const int l15  = lane & 15;
    const int wm   = (wave >> 1) * 64;
    const int wn   = (wave & 1) * 64;

    if (n0 < 512) {
#pragma unroll
        for (int j = 0; j < 4; ++j) {
            const int col = n0 + wn + j * 16 + l15;
            const float bv = bDKV[col];
#pragma unroll
            for (int i = 0; i < 4; ++i) {
                const int row = m0 + wm + i * 16 + quad * 4;
#pragma unroll
                for (int r = 0; r < 4; ++r) {
                    const float v = acc[i][j][r] + bv;
                    cKV_f[(size_t)(row + r) * 512 + col] = v;
                    cKVb [(size_t)(row + r) * 512 + col] = (bf16)v;
                }
            }
        }
    } else if (n0 < 2560) {
        const int odd = l15 & 1;
#pragma unroll
        for (int j = 0; j < 4; ++j) {
            const int col = n0 + wn + j * 16 + l15;
            const int cl  = col - 512;
            const float bv = bKR[cl];
            const float freq = exp2f(-(float)((cl & 127) >> 1) * INVF_C);
#pragma unroll
            for (int i = 0; i < 4; ++i) {
                const int rowb = m0 + wm + i * 16 + quad * 4;
#pragma unroll
                for (int r = 0; r < 4; ++r) {
                    const int row = rowb + r;
                    const float v = acc[i][j][r] + bv;
                    krc_f[(size_t)row * 2048 + cl] = v;
                    const float vp = __shfl_xor(v, 1, 64);
                    const float x1 = odd ? vp : v;
                    const float x2 = odd ? v  : vp;
                    const float ang = (float)(row & 2047) * freq;
                    float sn, cs;
                    __sincosf(ang, &sn, &cs);
                    kR[(size_t)row * 2048 + cl] =
                        (bf16)(odd ? (x1 * sn + x2 * cs) : (x1 * cs - x2 * sn));
                }
            }
        }
    } else {
#pragma unroll
        for (int j = 0; j < 4; ++j) {
            const int col = n0 + wn + j * 16 + l15;
            const int cl  = col - 2560;
            const float bv = bDQ[cl];
#pragma unroll
            for (int i = 0; i < 4; ++i) {
                const int row = m0 + wm + i * 16 + quad * 4;
#pragma unroll
                for (int r = 0; r < 4; ++r)
                    cQ[(size_t)(row + r) * 1536 + cl] = (bf16)(acc[i][j][r] + bv);
            }
        }
    }
}

// ---------------------------------------------------------------------------
// Batched GEMM #4+5: A=cKVb (4096x512), B=[W_UK^T|W_UV^T] (4096x512).
// Cols [0,2048) -> kC row-major; [2048,4096) -> vT transposed via LDS.
// ---------------------------------------------------------------------------
__global__ __launch_bounds__(256, 2)
void gemm_batch45(const bf16* __restrict__ A, const bf16* __restrict__ Wt45,
                  const float* __restrict__ bUK, const float* __restrict__ bUV,
                  bf16* __restrict__ kC, bf16* __restrict__ vT)
{
    __shared__ bf16 smem[128 * 136];
    bf16* As = smem;
    bf16* Bs = smem + 128 * 64;
    const int m0 = blockIdx.y * 128;
    const int n0 = blockIdx.x * 128;
    f32x4 acc[4][4] = {};
    gemm_core(A, Wt45, 512, m0, n0, As, Bs, acc);

    const int tid  = threadIdx.x;
    const int wave = tid >> 6;
    const int lane = tid & 63;
    const int quad = lane >> 4;
    const int l15  = lane & 15;
    const int wm   = (wave >> 1) * 64;
    const int wn   = (wave & 1) * 64;

    if (n0 < 2048) {
#pragma unroll
        for (int j = 0; j < 4; ++j) {
            const int col = n0 + wn + j * 16 + l15;
            const float bv = bUK[col];
#pragma unroll
            for (int i = 0; i < 4; ++i) {
                const int row = m0 + wm + i * 16 + quad * 4;
#pragma unroll
                for (int r = 0; r < 4; ++r)
                    kC[(size_t)(row + r) * 2048 + col] = (bf16)(acc[i][j][r] + bv);
            }
        }
    } else {
        __syncthreads();   // all waves done reading As/Bs -> reuse as scratch
        // stage: smem[vcol_local * 136 + s_local]
#pragma unroll
        for (int j = 0; j < 4; ++j) {
            const int cll = wn + j * 16 + l15;            // local v-col 0..127
            const float bv = bUV[n0 - 2048 + cll];
#pragma unroll
            for (int i = 0; i < 4; ++i) {
                const int sl = wm + i * 16 + quad * 4;    // local s 0..127
#pragma unroll
                for (int r = 0; r < 4; ++r)
                    smem[cll * 136 + sl + r] = (bf16)(acc[i][j][r] + bv);
            }
        }
        __syncthreads();
        // coalesced out: thread pair (2t,2t+1) covers one vT row's 128 s
        const int drow = tid >> 1;                        // local v-col
        const int s8   = (tid & 1) * 8;
        const int cl   = n0 - 2048 + drow;                // global v-col
        const int hloc = cl >> 7, d = cl & 127;
        const int bb   = m0 >> 11, s0 = m0 & 2047;
        bf16* dst = vT + ((size_t)((bb * 16 + hloc) * 128 + d)) * 2048 + s0;
#pragma unroll
        for (int c = 0; c < 8; ++c)
            *(bf16x8*)(dst + c * 16 + s8) = *(const bf16x8*)&smem[drow * 136 + c * 16 + s8];
    }
}

// ---------------------------------------------------------------------------
// qC GEMM with fused RoPE epilogue: writes qC = A@Wt+b (bf16) AND
// qR = rope(qC fp32) (bf16). Pair partner col^1 lives in lane l15^1.
// __sincosf (hw v_sin/v_cos): sincosf's Payne-Hanek slow path used scratch
// -> 845 MB WRITE_SIZE (round-3 post-mortem). Angle err ~2e-4 rad << bf16.
// ---------------------------------------------------------------------------
__global__ __launch_bounds__(256, 2)
void gemm_q_rope(const bf16* __restrict__ A, const bf16* __restrict__ Bt,
                 const float* __restrict__ bias,
                 bf16* __restrict__ qC, bf16* __restrict__ qR)
{
    __shared__ bf16 As[128 * 64];
    __shared__ bf16 Bs[128 * 64];
    const int m0 = blockIdx.y * 128;
    const int n0 = blockIdx.x * 128;
    f32x4 acc[4][4] = {};
    gemm_core(A, Bt, 1536, m0, n0, As, Bs, acc);

    const int tid  = threadIdx.x;
    const int wave = tid >> 6;
    const int lane = tid & 63;
    const int quad = lane >> 4;
    const int l15  = lane & 15;
    const int wm   = (wave >> 1) * 64;
    const int wn   = (wave & 1) * 64;
    const int odd  = l15 & 1;

#pragma unroll
    for (int j = 0; j < 4; ++j) {
        const int col = n0 + wn + j * 16 + l15;
        const float bv = bias[col];
        const float freq = exp2f(-(float)((col & 127) >> 1) * INVF_C);
#pragma unroll
        for (int i = 0; i < 4; ++i) {
            const int rowb = m0 + wm + i * 16 + quad * 4;
#pragma unroll
            for (int r = 0; r < 4; ++r) {
                const int row = rowb + r;
                const float v = acc[i][j][r] + bv;
                qC[(size_t)row * 2048 + col] = (bf16)v;
                const float vp = __shfl_xor(v, 1, 64);
                const float x1 = odd ? vp : v;
                const float x2 = odd ? v  : vp;
                const float ang = (float)(row & 2047) * freq;
                float sn, cs;
                __sincosf(ang, &sn, &cs);
                qR[(size_t)row * 2048 + col] =
                    (bf16)(odd ? (x1 * sn + x2 * cs) : (x1 * cs - x2 * sn));
            }
        }
    }
}

// ---------------------------------------------------------------------------
// Flash attention, causal. Split operands, all bf16:
//   qC,qR,kC,kR : (B*S, H*128) row-major;  Vt : (B*H, 128, S).
// Round-9 restructure: SPLIT-WAVE SYMMETRIC Q-TILES. Each block owns TWO
// 64-row q-tiles: a_lo = y (waves 0-3) and a_hi = 31-y (waves 4-7), of the
// 32 64-row q-tiles per (b,h). Per-block compute = 4(y+1)+4(32-y) = 132
// wave-tile-units for EVERY block (vs 16..256 spread before) -> no early
// block retirement starving the CU (round-8 Occupancy 22% vs 50% resident).
// Block remap y = yq<8 ? yq : 23-yq makes co-resident pair (y, 15-y):
// per-CU loop iterations 49 = constant. ntiles = 32-y covers both sub-tiles.
// Wave skip condition (kk0 <= wq+15) unchanged; all else param'd by wq.
// launch_bounds(512,2): 2 blocks/CU; (512,4) spilled (round-1).
// No setprio/defer-max (regressed round 5). T14 async-stage (round 6, +7us).
// LDS: Ks 64x264 + Vs 128x72 + Ps 128x72 = 70656 B.
// ---------------------------------------------------------------------------
__global__ __launch_bounds__(512, 2)
void mla_attn(const bf16* __restrict__ qCp, const bf16* __restrict__ qRp,
              const bf16* __restrict__ kCp, const bf16* __restrict__ kRp,
              const bf16* __restrict__ Vt, bf16* __restrict__ ctx)
{
    __shared__ bf16 Ks[64 * 264];
    __shared__ bf16 Vs[128 * 72];
    __shared__ bf16 Ps[128 * 72];
    const int bh   = blockIdx.x;
    const int b    = bh >> 4, hh = bh & 15;
    const int yq   = blockIdx.y;
    const int y    = (yq < 8) ? yq : 23 - yq;   // co-resident pair (y, 15-y)
    const int tid  = threadIdx.x;
    const int wave = tid >> 6;
    const int lane = tid & 63;
    const int quad = lane >> 4;
    const int l15  = lane & 15;
    // wave 0-3 -> q-tile y; wave 4-7 -> q-tile 31-y (16 q-rows per wave)
    const int wq   = (wave < 4) ? (y * 64 + wave * 16)
                               : ((31 - y) * 64 + (wave - 4) * 16);

    // Q fragments resident (A-operand: m=lane&15, k=quad*8+j).
    bf16x8 qf[8];
    {
        const size_t qoff = ((size_t)(b * 2048 + wq + l15)) * 2048
                          + hh * 128 + quad * 8;
#pragma unroll
        for (int ks = 0; ks < 4; ++ks) {
            qf[ks]     = *(const bf16x8*)(qCp + qoff + ks * 32);
            qf[4 + ks] = *(const bf16x8*)(qRp + qoff + ks * 32);
        }
    }

    float mstate[4], lstate[4];
    f32x4 o[8];
#pragma unroll
    for (int r = 0; r < 4; ++r) { mstate[r] = -1e30f; lstate[r] = 0.0f; }
#pragma unroll
    for (int dt = 0; dt < 8; ++dt) { f32x4 z = {0.f, 0.f, 0.f, 0.f}; o[dt] = z; }

    const int krow = tid >> 4, kcol = (tid & 15) * 8;   // K staging (512 thr)
    const int vsr  = tid >> 3, vsc  = (tid & 7) * 8;    // V staging

    // T14 staging registers (6 x bf16x8 = 24 VGPR)
    bf16x8 stKC[2], stKR[2], stV[2];

    const int ntiles = 32 - y;    // covers a_hi = 31-y (and a_lo = y <= 15)

    // prologue: load tile 0 into regs, write LDS, sync
    {
#pragma unroll
        for (int it = 0; it < 2; ++it) {
            const int row = it * 32 + krow;
            const size_t g = ((size_t)(b * 2048 + row)) * 2048 + hh * 128 + kcol;
            stKC[it] = *(const bf16x8*)(kCp + g);
            stKR[it] = *(const bf16x8*)(kRp + g);
        }
#pragma unroll
        for (int it = 0; it < 2; ++it) {
            const int d = it * 64 + vsr;
            stV[it] = *(const bf16x8*)(Vt + ((size_t)(bh * 128 + d)) * 2048 + vsc);
        }
#pragma unroll
        for (int it = 0; it < 2; ++it) {
            const int row = it * 32 + krow;
            *(bf16x8*)&Ks[row * 264 + kcol]       = stKC[it];
            *(bf16x8*)&Ks[row * 264 + 128 + kcol] = stKR[it];
        }
#pragma unroll
        for (int it = 0; it < 2; ++it) {
            const int d = it * 64 + vsr;
            *(bf16x8*)&Vs[d * 72 + vsc] = stV[it];
        }
    }
    __syncthreads();

    for (int t = 0; t < ntiles; ++t) {
        const int kk0 = t * 64;

        // T14: issue next tile's global loads; latency hides under compute(t)
        if (t + 1 < ntiles) {
            const int nk0 = kk0 + 64;
#pragma unroll
            for (int it = 0; it < 2; ++it) {
                const int row = it * 32 + krow;
                const size_t g = ((size_t)(b * 2048 + nk0 + row)) * 2048 + hh * 128 + kcol;
                stKC[it] = *(const bf16x8*)(kCp + g);
                stKR[it] = *(const bf16x8*)(kRp + g);
            }
#pragma unroll
            for (int it = 0; it < 2; ++it) {
                const int d = it * 64 + vsr;
                stV[it] = *(const bf16x8*)(Vt + ((size_t)(bh * 128 + d)) * 2048 + nk0 + vsc);
            }
        }

        if (kk0 <= wq + 15) {   // wave-uniform: tile not fully masked
            f32x4 sc[4] = {};
#pragma unroll
            for (int ks = 0; ks < 8; ++ks)
#pragma unroll
                for (int j = 0; j < 4; ++j) {
                    bf16x8 kf = *(const bf16x8*)&Ks[(j * 16 + l15) * 264 + ks * 32 + quad * 8];
                    sc[j] = __builtin_amdgcn_mfma_f32_16x16x32_bf16(qf[ks], kf, sc[j], 0, 0, 0);
                }

            const bool diag = (kk0 + 63 > wq);
            float rowmax[4] = {-1e30f, -1e30f, -1e30f, -1e30f};
#pragma unroll
            for (int j = 0; j < 4; ++j) {
                const int kkcol = kk0 + j * 16 + l15;
#pragma unroll
                for (int r = 0; r < 4; ++r) {
                    float s = sc[j][r] * 0.0625f;             // 1/sqrt(256)
                    if (diag && (kkcol > wq + quad * 4 + r)) s = -1e30f;
                    sc[j][r] = s;
                    rowmax[r] = fmaxf(rowmax[r], s);
                }
            }
#pragma unroll
            for (int r = 0; r < 4; ++r) {  // reduce across the 16 col-lanes
                float v = rowmax[r];
                v = fmaxf(v, __shfl_xor(v, 1, 64));
                v = fmaxf(v, __shfl_xor(v, 2, 64));
                v = fmaxf(v, __shfl_xor(v, 4, 64));
                v = fmaxf(v, __shfl_xor(v, 8, 64));
                rowmax[r] = v;
            }
            float alpha[4];
#pragma unroll
            for (int r = 0; r < 4; ++r) {
                const float mnew = fmaxf(mstate[r], rowmax[r]);
                alpha[r] = __expf(mstate[r] - mnew);
                mstate[r] = mnew;
            }
            float rowsum[4] = {0.f, 0.f, 0.f, 0.f};
#pragma unroll
            for (int j = 0; j < 4; ++j)
#pragma unroll
                for (int r = 0; r < 4; ++r) {
                    const float p = __expf(sc[j][r] - mstate[r]);
                    sc[j][r] = p;
                    rowsum[r] += p;
                }
#pragma unroll
            for (int r = 0; r < 4; ++r) {
                float v = rowsum[r];
                v += __shfl_xor(v, 1, 64);
                v += __shfl_xor(v, 2, 64);
                v += __shfl_xor(v, 4, 64);
                v += __shfl_xor(v, 8, 64);
                lstate[r] = lstate[r] * alpha[r] + v;
            }
            // P: C-layout -> LDS -> A-operand layout (verified, m120)
#pragma unroll
            for (int j = 0; j < 4; ++j)
#pragma unroll
                for (int r = 0; r < 4; ++r)
                    Ps[(wave * 16 + quad * 4 + r) * 72 + j * 16 + l15] = (bf16)sc[j][r];
#pragma unroll
            for (int dt = 0; dt < 8; ++dt)
#pragma unroll
                for (int r = 0; r < 4; ++r)
                    o[dt][r] *= alpha[r];
#pragma unroll
            for (int ks2 = 0; ks2 < 2; ++ks2) {
                bf16x8 pf = *(const bf16x8*)&Ps[(wave * 16 + l15) * 72 + ks2 * 32 + quad * 8];
#pragma unroll
                for (int dt = 0; dt < 8; ++dt) {
                    bf16x8 vf = *(const bf16x8*)&Vs[(dt * 16 + l15) * 72 + ks2 * 32 + quad * 8];
                    o[dt] = __builtin_amdgcn_mfma_f32_16x16x32_bf16(pf, vf, o[dt], 0, 0, 0);
                }
            }
        }

        __syncthreads();   // everyone done reading Ks/Vs of tile t
        if (t + 1 < ntiles) {
            // T14: LDS write of the prefetched tile (vmcnt drained on use)
#pragma unroll
            for (int it = 0; it < 2; ++it) {
                const int row = it * 32 + krow;
                *(bf16x8*)&Ks[row * 264 + kcol]       = stKC[it];
                *(bf16x8*)&Ks[row * 264 + 128 + kcol] = stKR[it];
            }
#pragma unroll
            for (int it = 0; it < 2; ++it) {
                const int d = it * 64 + vsr;
                *(bf16x8*)&Vs[d * 72 + vsc] = stV[it];
            }
        }
        __syncthreads();   // staged data visible for tile t+1
    }

    float inv_l[4];
#pragma unroll
    for (int r = 0; r < 4; ++r) inv_l[r] = 1.0f / lstate[r];
#pragma unroll
    for (int dt = 0; dt < 8; ++dt) {
        const int d = dt * 16 + l15;
#pragma unroll
        for (int r = 0; r < 4; ++r) {
            const int q = wq + quad * 4 + r;
            ctx[((size_t)(b * 2048 + q)) * 2048 + hh * 128 + d] = (bf16)(o[dt][r] * inv_l[r]);
        }
    }
}

// ---------------------------------------------------------------------------
extern "C" void kernel_launch(void* const* d_in, const int* in_sizes, int n_in,
                              void* d_out, int out_size, void* d_ws, size_t ws_size,
                              hipStream_t stream)
{
    const float* h     = (const float*)d_in[0];
    const float* W_DKV = (const float*)d_in[1];
    const float* b_DKV = (const float*)d_in[2];
    const float* W_UK  = (const float*)d_in[3];
    const float* b_UK  = (const float*)d_in[4];
    const float* W_UV  = (const float*)d_in[5];
    const float* b_UV  = (const float*)d_in[6];
    const float* W_DQ  = (const float*)d_in[7];
    const float* b_DQ  = (const float*)d_in[8];
    const float* W_UQ  = (const float*)d_in[9];
    const float* b_UQ  = (const float*)d_in[10];
    const float* W_KR  = (const float*)d_in[11];
    const float* b_KR  = (const float*)d_in[12];
    const float* W_O   = (const float*)d_in[13];
    const float* b_O   = (const float*)d_in[14];

    float* out   = (float*)d_out;             // (4096, 2048)  output 0, fp32
    float* cKV_f = out + (size_t)8388608;     // (4096, 512)   output 1
    float* krc_f = out + (size_t)10485760;    // (4096, 2048)  output 2

    // out-proper (33.5 MB) is dead until the final GEMM -> park qC + qR
    // there; both consumed by mla_attn before the final GEMM overwrites.
    bf16* qC = (bf16*)d_out;                  // (B*S, H*128)
    bf16* qR = (bf16*)d_out + 8388608;        // (B*S, H*128)

    // ws slots (bf16 el):
    //  hb    @0       8.4M  cast -> batch1 A; DEAD after -> vT (batch45 out)
    //  cKVb  @8.4M    2.1M  batch1 -> batch45          \ after q_rope both
    //  cQ    @10.5M   6.3M  batch1 -> gemm_q            > dead -> ctx 8.4M
    //  WtAll @16.8M   8.4M  tc3 -> b1; tc2 -> b45; tcUQ -> q; tcWO -> final
    //  kR    @25.2M   8.4M  batch1 (fused rope) -> attn
    //  kC    @33.6M   8.4M  batch45 -> attn
    bf16* ws    = (bf16*)d_ws;
    bf16* hb    = ws + 0;
    bf16* cKVb  = ws + 8388608;
    bf16* cQ    = ws + 10485760;
    bf16* WtAll = ws + 16777216;
    bf16* kR    = ws + 25165824;
    bf16* kC    = ws + 33554432;
    bf16* vT    = hb;              // hb dead after batch1
    bf16* ctx   = ws + 8388608;    // cKVb+cQ dead after gemm_q_rope

    dim3 tb(32, 8);

    cast_to_bf16<<<8192, 256, 0, stream>>>(h, hb, 8388608);

    // WtAll rows: [0,512)=W_DKV^T, [512,2560)=W_KR^T, [2560,4096)=W_DQ^T
    transpose_cast3<<<dim3(128, 64), tb, 0, stream>>>(W_DKV, W_KR, W_DQ, WtAll);

    gemm_batch1<<<dim3(32, 32), 256, 0, stream>>>(hb, WtAll, b_DKV, b_KR, b_DQ,
                                                  cKV_f, cKVb, krc_f, kR, cQ);
    // hb dead from here

    // Wt45 rows: [0,2048)=W_UK^T, [2048,4096)=W_UV^T (K=512)
    transpose_cast2<<<dim3(128, 16), tb, 0, stream>>>(W_UK, W_UV, WtAll);
    gemm_batch45<<<dim3(32, 32), 256, 0, stream>>>(cKVb, WtAll, b_UK, b_UV, kC, vT);

    transpose_cast<<<dim3(64, 48), tb, 0, stream>>>(W_UQ, WtAll, 1536, 2048);
    gemm_q_rope<<<dim3(16, 32), 256, 0, stream>>>(cQ, WtAll, b_UQ, qC, qR);

    mla_attn<<<dim3(32, 16), 512, 0, stream>>>(qC, qR, kC, kR, vT, ctx);

    transpose_cast<<<dim3(64, 64), tb, 0, stream>>>(W_O, WtAll, 2048, 2048);
    gemm_bt<<<dim3(16, 32), 256, 0, stream>>>(ctx, WtAll, b_O, out, nullptr, 4096, 2048, 2048);
}

// Round 10
// 537.908 us; speedup vs baseline: 1.0764x; 1.0764x over previous
//
#include <hip/hip_runtime.h>
#include <cstdint>
#include <cstddef>

typedef __bf16 bf16;
typedef __bf16 bf16x8 __attribute__((ext_vector_type(8)));
typedef float  f32x4  __attribute__((ext_vector_type(4)));

#define INVF_C 0.20762050593046014f   // log2(10000)/64

// global -> LDS async copy, 16B per lane. LDS base must be wave-uniform;
// HW scatters lane i at base + 16*i. (m97-verified pattern.)
__device__ __forceinline__ void async_copy16(const void* g, void* l)
{
    auto gp = (__attribute__((address_space(1))) const void*)(reinterpret_cast<uintptr_t>(g));
    auto lp = (__attribute__((address_space(3))) void*)(uint32_t)(reinterpret_cast<uintptr_t>(l));
    __builtin_amdgcn_global_load_lds(gp, lp, 16, 0, 0);
}

// ---------------------------------------------------------------------------
// elementwise fp32 -> bf16 cast, 4 elems/thread, n % 4 == 0
// ---------------------------------------------------------------------------
__global__ void cast_to_bf16(const float* __restrict__ in, bf16* __restrict__ out, int n)
{
    const int i = (blockIdx.x * 256 + threadIdx.x) * 4;
    if (i < n) {
        const float4 v = *(const float4*)(in + i);
        out[i]     = (bf16)v.x;
        out[i + 1] = (bf16)v.y;
        out[i + 2] = (bf16)v.z;
        out[i + 3] = (bf16)v.w;
    }
}

// ---------------------------------------------------------------------------
// fused transpose + cast: out[c*R + r] = (bf16)in[r*C + c]; in is RxC fp32.
// grid (C/32, R/32), block (32,8).  (round-4 version — verified best)
// ---------------------------------------------------------------------------
__global__ void transpose_cast(const float* __restrict__ in, bf16* __restrict__ out,
                               int R, int Ccols)
{
    __shared__ float tile[32][33];
    const int c0 = blockIdx.x * 32;
    const int r0 = blockIdx.y * 32;
    const int tx = threadIdx.x, ty = threadIdx.y;
    for (int i = ty; i < 32; i += 8)
        tile[i][tx] = in[(size_t)(r0 + i) * Ccols + c0 + tx];
    __syncthreads();
    for (int i = ty; i < 32; i += 8)
        out[(size_t)(c0 + i) * R + r0 + tx] = (bf16)tile[tx][i];
}

// ---------------------------------------------------------------------------
// Shared GEMM main loop (m97 structure): 128x128 tile, BK=64, 4 waves 2x2,
// global_load_lds width-16 staging into unpadded LDS. Verified rounds 0-8.
// No XCD swizzle: operands are L3-resident (round-5 regression; m160).
// ---------------------------------------------------------------------------
__device__ __forceinline__ void gemm_core(const bf16* __restrict__ A,
                                          const bf16* __restrict__ Bt,
                                          int K, int m0, int n0,
                                          bf16* As, bf16* Bs,
                                          f32x4 (&acc)[4][4])
{
    const int tid  = threadIdx.x;
    const int wave = tid >> 6;
    const int lane = tid & 63;
    const int quad = lane >> 4;
    const int l15  = lane & 15;
    const int wm   = (wave >> 1) * 64;
    const int wn   = (wave & 1) * 64;

    // staging: wave w covers rows [w*32, w*32+32) in 4 issues of 8 rows;
    // lane l -> row l>>3, col chunk (l&7)*8 (matches lane*16B LDS scatter)
    const int srow = lane >> 3;
    const int scol = (lane & 7) * 8;
    const bf16* Ab = A  + (size_t)(m0 + wave * 32 + srow) * K + scol;
    const bf16* Bb = Bt + (size_t)(n0 + wave * 32 + srow) * K + scol;
    bf16* AsW = &As[(wave * 32) * 64];
    bf16* BsW = &Bs[(wave * 32) * 64];

    for (int k0 = 0; k0 < K; k0 += 64) {
        __syncthreads();   // previous tile fully consumed
#pragma unroll
        for (int i = 0; i < 4; ++i) {
            async_copy16(Ab + (size_t)(i * 8) * K + k0, AsW + i * 8 * 64);
            async_copy16(Bb + (size_t)(i * 8) * K + k0, BsW + i * 8 * 64);
        }
        __syncthreads();   // drains vmcnt(0) -> staged data visible
#pragma unroll
        for (int ks = 0; ks < 2; ++ks) {
            bf16x8 af[4], bfr[4];
#pragma unroll
            for (int i = 0; i < 4; ++i)
                af[i] = *(const bf16x8*)&As[(wm + i * 16 + l15) * 64 + ks * 32 + quad * 8];
#pragma unroll
            for (int j = 0; j < 4; ++j)
                bfr[j] = *(const bf16x8*)&Bs[(wn + j * 16 + l15) * 64 + ks * 32 + quad * 8];
#pragma unroll
            for (int i = 0; i < 4; ++i)
#pragma unroll
                for (int j = 0; j < 4; ++j)
                    acc[i][j] = __builtin_amdgcn_mfma_f32_16x16x32_bf16(af[i], bfr[j], acc[i][j], 0, 0, 0);
        }
    }
}

// ---------------------------------------------------------------------------
// Generic C[M,N] = A @ Bt^T + bias; dual fp32/bf16 epilogue (final GEMM).
// ---------------------------------------------------------------------------
__global__ __launch_bounds__(256, 2)
void gemm_bt(const bf16* __restrict__ A, const bf16* __restrict__ Bt,
             const float* __restrict__ bias, float* __restrict__ C,
             bf16* __restrict__ Cb, int M, int N, int K)
{
    __shared__ bf16 As[128 * 64];
    __shared__ bf16 Bs[128 * 64];
    const int m0 = blockIdx.y * 128;
    const int n0 = blockIdx.x * 128;
    f32x4 acc[4][4] = {};
    gemm_core(A, Bt, K, m0, n0, As, Bs, acc);

    const int tid  = threadIdx.x;
    const int wave = tid >> 6;
    const int lane = tid & 63;
    const int quad = lane >> 4;
    const int l15  = lane & 15;
    const int wm   = (wave >> 1) * 64;
    const int wn   = (wave & 1) * 64;

    // C/D layout: col = lane&15, row = quad*4 + r (verified m89/m91)
#pragma unroll
    for (int j = 0; j < 4; ++j) {
        const int col = n0 + wn + j * 16 + l15;
        const float bv = bias[col];
#pragma unroll
        for (int i = 0; i < 4; ++i) {
            const int row = m0 + wm + i * 16 + quad * 4;
#pragma unroll
            for (int r = 0; r < 4; ++r) {
                const float v = acc[i][j][r] + bv;
                if (C)  C [(size_t)(row + r) * N + col] = v;
                if (Cb) Cb[(size_t)(row + r) * N + col] = (bf16)v;
            }
        }
    }
}

// ---------------------------------------------------------------------------
// Batched GEMM #1: A=hb (4096x2048), B = [W_DKV^T | W_KR^T | W_DQ^T]
// stacked as WtAll (4096 x 2048). N=4096 -> 1024 blocks (full device).
// Section epilogues: cols [0,512) -> cKV fp32+bf16; [512,2560) -> krc fp32;
// [2560,4096) -> cQ bf16. Section boundaries are multiples of 128.
// ---------------------------------------------------------------------------
__global__ __launch_bounds__(256, 2)
void gemm_batch1(const bf16* __restrict__ A, const bf16* __restrict__ WtAll,
                 const float* __restrict__ bDKV, const float* __restrict__ bKR,
                 const float* __restrict__ bDQ,
                 float* __restrict__ cKV_f, bf16* __restrict__ cKVb,
                 float* __restrict__ krc_f, bf16* __restrict__ cQ)
{
    __shared__ bf16 As[128 * 64];
    __shared__ bf16 Bs[128 * 64];
    const int m0 = blockIdx.y * 128;
    const int n0 = blockIdx.x * 128;
    f32x4 acc[4][4] = {};
    gemm_core(A, WtAll, 2048, m0, n0, As, Bs, acc);

    const int tid  = threadIdx.x;
    const int wave = tid >> 6;
    const int lane = tid & 63;
    const int quad = lane >> 4;
    const int l15  = lane & 15;
    const int wm   = (wave >> 1) * 64;
    const int wn   = (wave & 1) * 64;

    if (n0 < 512) {
#pragma unroll
        for (int j = 0; j < 4; ++j) {
            const int col = n0 + wn + j * 16 + l15;
            const float bv = bDKV[col];
#pragma unroll
            for (int i = 0; i < 4; ++i) {
                const int row = m0 + wm + i * 16 + quad * 4;
#pragma unroll
                for (int r = 0; r < 4; ++r) {
                    const float v = acc[i][j][r] + bv;
                    cKV_f[(size_t)(row + r) * 512 + col] = v;
                    cKVb [(size_t)(row + r) * 512 + col] = (bf16)v;
                }
            }
        }
    } else if (n0 < 2560) {
#pragma unroll
        for (int j = 0; j < 4; ++j) {
            const int col = n0 + wn + j * 16 + l15;
            const int cl  = col - 512;
            const float bv = bKR[cl];
#pragma unroll
            for (int i = 0; i < 4; ++i) {
                const int row = m0 + wm + i * 16 + quad * 4;
#pragma unroll
                for (int r = 0; r < 4; ++r)
                    krc_f[(size_t)(row + r) * 2048 + cl] = acc[i][j][r] + bv;
            }
        }
    } else {
#pragma unroll
        for (int j = 0; j < 4; ++j) {
            const int col = n0 + wn + j * 16 + l15;
            const int cl  = col - 2560;
            const float bv = bDQ[cl];
#pragma unroll
            for (int i = 0; i < 4; ++i) {
                const int row = m0 + wm + i * 16 + quad * 4;
#pragma unroll
                for (int r = 0; r < 4; ++r)
                    cQ[(size_t)(row + r) * 1536 + cl] = (bf16)(acc[i][j][r] + bv);
            }
        }
    }
}

// ---------------------------------------------------------------------------
// Batched GEMM #4+5: A=cKVb (4096x512), B = [W_UK^T | W_UV^T] (4096x512).
// Cols [0,2048) -> kC; [2048,4096) -> vC. Both bf16.
// ---------------------------------------------------------------------------
__global__ __launch_bounds__(256, 2)
void gemm_batch45(const bf16* __restrict__ A, const bf16* __restrict__ Wt45,
                  const float* __restrict__ bUK, const float* __restrict__ bUV,
                  bf16* __restrict__ kC, bf16* __restrict__ vC)
{
    __shared__ bf16 As[128 * 64];
    __shared__ bf16 Bs[128 * 64];
    const int m0 = blockIdx.y * 128;
    const int n0 = blockIdx.x * 128;
    f32x4 acc[4][4] = {};
    gemm_core(A, Wt45, 512, m0, n0, As, Bs, acc);

    const int tid  = threadIdx.x;
    const int wave = tid >> 6;
    const int lane = tid & 63;
    const int quad = lane >> 4;
    const int l15  = lane & 15;
    const int wm   = (wave >> 1) * 64;
    const int wn   = (wave & 1) * 64;

    const bool isK = (n0 < 2048);
    bf16* outp = isK ? kC : vC;
    const float* bp = isK ? bUK : bUV;
    const int base = isK ? 0 : 2048;
#pragma unroll
    for (int j = 0; j < 4; ++j) {
        const int col = n0 + wn + j * 16 + l15;
        const int cl  = col - base;
        const float bv = bp[cl];
#pragma unroll
        for (int i = 0; i < 4; ++i) {
            const int row = m0 + wm + i * 16 + quad * 4;
#pragma unroll
            for (int r = 0; r < 4; ++r)
                outp[(size_t)(row + r) * 2048 + cl] = (bf16)(acc[i][j][r] + bv);
        }
    }
}

// ---------------------------------------------------------------------------
// qC GEMM with fused RoPE epilogue: writes qC = A@Wt+b (bf16) AND
// qR = rope(qC fp32) (bf16). Pair partner col^1 lives in lane l15^1.
// __sincosf (hw v_sin/v_cos): sincosf's Payne-Hanek slow path used scratch
// -> 845 MB WRITE_SIZE (round-3 post-mortem). Angle err ~2e-4 rad << bf16.
// ---------------------------------------------------------------------------
__global__ __launch_bounds__(256, 2)
void gemm_q_rope(const bf16* __restrict__ A, const bf16* __restrict__ Bt,
                 const float* __restrict__ bias,
                 bf16* __restrict__ qC, bf16* __restrict__ qR)
{
    __shared__ bf16 As[128 * 64];
    __shared__ bf16 Bs[128 * 64];
    const int m0 = blockIdx.y * 128;
    const int n0 = blockIdx.x * 128;
    f32x4 acc[4][4] = {};
    gemm_core(A, Bt, 1536, m0, n0, As, Bs, acc);

    const int tid  = threadIdx.x;
    const int wave = tid >> 6;
    const int lane = tid & 63;
    const int quad = lane >> 4;
    const int l15  = lane & 15;
    const int wm   = (wave >> 1) * 64;
    const int wn   = (wave & 1) * 64;
    const int odd  = l15 & 1;

#pragma unroll
    for (int j = 0; j < 4; ++j) {
        const int col = n0 + wn + j * 16 + l15;
        const float bv = bias[col];
        const float freq = exp2f(-(float)((col & 127) >> 1) * INVF_C);
#pragma unroll
        for (int i = 0; i < 4; ++i) {
            const int rowb = m0 + wm + i * 16 + quad * 4;
#pragma unroll
            for (int r = 0; r < 4; ++r) {
                const int row = rowb + r;
                const float v = acc[i][j][r] + bv;
                qC[(size_t)row * 2048 + col] = (bf16)v;
                const float vp = __shfl_xor(v, 1, 64);
                const float x1 = odd ? vp : v;
                const float x2 = odd ? v  : vp;
                const float ang = (float)(row & 2047) * freq;
                float sn, cs;
                __sincosf(ang, &sn, &cs);
                qR[(size_t)row * 2048 + col] =
                    (bf16)(odd ? (x1 * sn + x2 * cs) : (x1 * cs - x2 * sn));
            }
        }
    }
}

// vC (B*S, H*128) bf16 -> vT (B*H, 128, S). grid (S/32, 128/32, 32), block (32,8)
__global__ void transpose_v(const bf16* __restrict__ vC, bf16* __restrict__ vT)
{
    __shared__ bf16 tile[32][33];
    const int bh = blockIdx.z, b = bh >> 4, h = bh & 15;
    const int s0 = blockIdx.x * 32, d0 = blockIdx.y * 32;
    const int tx = threadIdx.x, ty = threadIdx.y;
    for (int i = ty; i < 32; i += 8)
        tile[i][tx] = vC[((size_t)(b * 2048 + s0 + i)) * 2048 + h * 128 + d0 + tx];
    __syncthreads();
    for (int i = ty; i < 32; i += 8)
        vT[((size_t)(bh * 128 + d0 + i)) * 2048 + s0 + tx] = tile[tx][i];
}

// ---------------------------------------------------------------------------
// per-head interleaved RoPE (kR path), layout (B*S, H*128), fp32 input.
// __sincosf: no scratch slow path (round-3 post-mortem).
// ---------------------------------------------------------------------------
__global__ void rope_heads_f(const float* __restrict__ in, bf16* __restrict__ out)
{
    const int idx = blockIdx.x * 256 + threadIdx.x;     // 2*2048*16*64 total
    const int j = idx & 63;
    const int h = (idx >> 6) & 15;
    const int s = (idx >> 10) & 2047;
    const int b = idx >> 21;
    const size_t src = ((size_t)(b * 2048 + s)) * 2048 + h * 128 + 2 * j;
    const float x1 = in[src], x2 = in[src + 1];
    const float ang = (float)s * exp2f(-(float)j * INVF_C);
    float sn, cs;
    __sincosf(ang, &sn, &cs);
    out[src]     = (bf16)(x1 * cs - x2 * sn);
    out[src + 1] = (bf16)(x1 * sn + x2 * cs);
}

// ---------------------------------------------------------------------------
// Flash attention, causal. Split operands, all bf16:
//   qC,qR,kC,kR : (B*S, H*128) row-major;  Vt : (B*H, 128, S).
// BQ=128 (8 waves x 16 q-rows, wave-local softmax), BKV=64.
// Grid (bh=32, y=16): 512 blocks, 2/CU -> all co-resident.
// Balance remap: co-resident pair (y, y+8) -> q-tiles (2y, 15-2y) -> constant
// 34 KV-tile-units per CU (verified round 2: 159 -> 138 us).
// launch_bounds(512,2): 2 blocks/CU; (512,4) spilled (round-1 post-mortem).
// No setprio / no defer-max (regressed round 5; 8-wave lockstep = m190 null).
// No split-wave symmetric tiles (round-9: +44% staging iterations, 174 us).
// T14 async-stage verified round 6 (134 -> 127 us, VGPR 84, no spill).
// LDS: Ks 64x264 + Vs 128x72 + Ps 128x72 = 70656 B.
// ---------------------------------------------------------------------------
__global__ __launch_bounds__(512, 2)
void mla_attn(const bf16* __restrict__ qCp, const bf16* __restrict__ qRp,
              const bf16* __restrict__ kCp, const bf16* __restrict__ kRp,
              const bf16* __restrict__ Vt, bf16* __restrict__ ctx)
{
    __shared__ bf16 Ks[64 * 264];
    __shared__ bf16 Vs[128 * 72];
    __shared__ bf16 Ps[128 * 72];
    const int bh   = blockIdx.x;
    const int b    = bh >> 4, hh = bh & 15;
    const int yq   = blockIdx.y;
    const int qt   = (yq < 8) ? (2 * yq) : (31 - 2 * yq);   // balance remap
    const int q0   = qt * 128;
    const int tid  = threadIdx.x;
    const int wave = tid >> 6;
    const int lane = tid & 63;
    const int quad = lane >> 4;
    const int l15  = lane & 15;
    const int wq   = q0 + wave * 16;       // wave's first q row

    // Q fragments resident (A-operand: m=lane&15, k=quad*8+j).
    bf16x8 qf[8];
    {
        const size_t qoff = ((size_t)(b * 2048 + wq + l15)) * 2048
                          + hh * 128 + quad * 8;
#pragma unroll
        for (int ks = 0; ks < 4; ++ks) {
            qf[ks]     = *(const bf16x8*)(qCp + qoff + ks * 32);
            qf[4 + ks] = *(const bf16x8*)(qRp + qoff + ks * 32);
        }
    }

    float mstate[4], lstate[4];
    f32x4 o[8];
#pragma unroll
    for (int r = 0; r < 4; ++r) { mstate[r] = -1e30f; lstate[r] = 0.0f; }
#pragma unroll
    for (int dt = 0; dt < 8; ++dt) { f32x4 z = {0.f, 0.f, 0.f, 0.f}; o[dt] = z; }

    const int krow = tid >> 4, kcol = (tid & 15) * 8;   // K staging (512 thr)
    const int vsr  = tid >> 3, vsc  = (tid & 7) * 8;    // V staging

    // T14 staging registers (6 x bf16x8 = 24 VGPR)
    bf16x8 stKC[2], stKR[2], stV[2];

    const int ntiles = 2 * qt + 2;

    // prologue: load tile 0 into regs, write LDS, sync
    {
#pragma unroll
        for (int it = 0; it < 2; ++it) {
            const int row = it * 32 + krow;
            const size_t g = ((size_t)(b * 2048 + row)) * 2048 + hh * 128 + kcol;
            stKC[it] = *(const bf16x8*)(kCp + g);
            stKR[it] = *(const bf16x8*)(kRp + g);
        }
#pragma unroll
        for (int it = 0; it < 2; ++it) {
            const int d = it * 64 + vsr;
            stV[it] = *(const bf16x8*)(Vt + ((size_t)(bh * 128 + d)) * 2048 + vsc);
        }
#pragma unroll
        for (int it = 0; it < 2; ++it) {
            const int row = it * 32 + krow;
            *(bf16x8*)&Ks[row * 264 + kcol]       = stKC[it];
            *(bf16x8*)&Ks[row * 264 + 128 + kcol] = stKR[it];
        }
#pragma unroll
        for (int it = 0; it < 2; ++it) {
            const int d = it * 64 + vsr;
            *(bf16x8*)&Vs[d * 72 + vsc] = stV[it];
        }
    }
    __syncthreads();

    for (int t = 0; t < ntiles; ++t) {
        const int kk0 = t * 64;

        // T14: issue next tile's global loads; latency hides under compute(t)
        if (t + 1 < ntiles) {
            const int nk0 = kk0 + 64;
#pragma unroll
            for (int it = 0; it < 2; ++it) {
                const int row = it * 32 + krow;
                const size_t g = ((size_t)(b * 2048 + nk0 + row)) * 2048 + hh * 128 + kcol;
                stKC[it] = *(const bf16x8*)(kCp + g);
                stKR[it] = *(const bf16x8*)(kRp + g);
            }
#pragma unroll
            for (int it = 0; it < 2; ++it) {
                const int d = it * 64 + vsr;
                stV[it] = *(const bf16x8*)(Vt + ((size_t)(bh * 128 + d)) * 2048 + nk0 + vsc);
            }
        }

        if (kk0 <= wq + 15) {   // wave-uniform: tile not fully masked
            f32x4 sc[4] = {};
#pragma unroll
            for (int ks = 0; ks < 8; ++ks)
#pragma unroll
                for (int j = 0; j < 4; ++j) {
                    bf16x8 kf = *(const bf16x8*)&Ks[(j * 16 + l15) * 264 + ks * 32 + quad * 8];
                    sc[j] = __builtin_amdgcn_mfma_f32_16x16x32_bf16(qf[ks], kf, sc[j], 0, 0, 0);
                }

            const bool diag = (kk0 + 63 > wq);
            float rowmax[4] = {-1e30f, -1e30f, -1e30f, -1e30f};
#pragma unroll
            for (int j = 0; j < 4; ++j) {
                const int kkcol = kk0 + j * 16 + l15;
#pragma unroll
                for (int r = 0; r < 4; ++r) {
                    float s = sc[j][r] * 0.0625f;             // 1/sqrt(256)
                    if (diag && (kkcol > wq + quad * 4 + r)) s = -1e30f;
                    sc[j][r] = s;
                    rowmax[r] = fmaxf(rowmax[r], s);
                }
            }
#pragma unroll
            for (int r = 0; r < 4; ++r) {  // reduce across the 16 col-lanes
                float v = rowmax[r];
                v = fmaxf(v, __shfl_xor(v, 1, 64));
                v = fmaxf(v, __shfl_xor(v, 2, 64));
                v = fmaxf(v, __shfl_xor(v, 4, 64));
                v = fmaxf(v, __shfl_xor(v, 8, 64));
                rowmax[r] = v;
            }
            float alpha[4];
#pragma unroll
            for (int r = 0; r < 4; ++r) {
                const float mnew = fmaxf(mstate[r], rowmax[r]);
                alpha[r] = __expf(mstate[r] - mnew);
                mstate[r] = mnew;
            }
            float rowsum[4] = {0.f, 0.f, 0.f, 0.f};
#pragma unroll
            for (int j = 0; j < 4; ++j)
#pragma unroll
                for (int r = 0; r < 4; ++r) {
                    const float p = __expf(sc[j][r] - mstate[r]);
                    sc[j][r] = p;
                    rowsum[r] += p;
                }
#pragma unroll
            for (int r = 0; r < 4; ++r) {
                float v = rowsum[r];
                v += __shfl_xor(v, 1, 64);
                v += __shfl_xor(v, 2, 64);
                v += __shfl_xor(v, 4, 64);
                v += __shfl_xor(v, 8, 64);
                lstate[r] = lstate[r] * alpha[r] + v;
            }
            // P: C-layout -> LDS -> A-operand layout (verified, m120)
#pragma unroll
            for (int j = 0; j < 4; ++j)
#pragma unroll
                for (int r = 0; r < 4; ++r)
                    Ps[(wave * 16 + quad * 4 + r) * 72 + j * 16 + l15] = (bf16)sc[j][r];
#pragma unroll
            for (int dt = 0; dt < 8; ++dt)
#pragma unroll
                for (int r = 0; r < 4; ++r)
                    o[dt][r] *= alpha[r];
#pragma unroll
            for (int ks2 = 0; ks2 < 2; ++ks2) {
                bf16x8 pf = *(const bf16x8*)&Ps[(wave * 16 + l15) * 72 + ks2 * 32 + quad * 8];
#pragma unroll
                for (int dt = 0; dt < 8; ++dt) {
                    bf16x8 vf = *(const bf16x8*)&Vs[(dt * 16 + l15) * 72 + ks2 * 32 + quad * 8];
                    o[dt] = __builtin_amdgcn_mfma_f32_16x16x32_bf16(pf, vf, o[dt], 0, 0, 0);
                }
            }
        }

        __syncthreads();   // everyone done reading Ks/Vs of tile t
        if (t + 1 < ntiles) {
            // T14: LDS write of the prefetched tile (vmcnt drained on use)
#pragma unroll
            for (int it = 0; it < 2; ++it) {
                const int row = it * 32 + krow;
                *(bf16x8*)&Ks[row * 264 + kcol]       = stKC[it];
                *(bf16x8*)&Ks[row * 264 + 128 + kcol] = stKR[it];
            }
#pragma unroll
            for (int it = 0; it < 2; ++it) {
                const int d = it * 64 + vsr;
                *(bf16x8*)&Vs[d * 72 + vsc] = stV[it];
            }
        }
        __syncthreads();   // staged data visible for tile t+1
    }

    float inv_l[4];
#pragma unroll
    for (int r = 0; r < 4; ++r) inv_l[r] = 1.0f / lstate[r];
#pragma unroll
    for (int dt = 0; dt < 8; ++dt) {
        const int d = dt * 16 + l15;
#pragma unroll
        for (int r = 0; r < 4; ++r) {
            const int q = wq + quad * 4 + r;
            ctx[((size_t)(b * 2048 + q)) * 2048 + hh * 128 + d] = (bf16)(o[dt][r] * inv_l[r]);
        }
    }
}

// ---------------------------------------------------------------------------
extern "C" void kernel_launch(void* const* d_in, const int* in_sizes, int n_in,
                              void* d_out, int out_size, void* d_ws, size_t ws_size,
                              hipStream_t stream)
{
    const float* h     = (const float*)d_in[0];
    const float* W_DKV = (const float*)d_in[1];
    const float* b_DKV = (const float*)d_in[2];
    const float* W_UK  = (const float*)d_in[3];
    const float* b_UK  = (const float*)d_in[4];
    const float* W_UV  = (const float*)d_in[5];
    const float* b_UV  = (const float*)d_in[6];
    const float* W_DQ  = (const float*)d_in[7];
    const float* b_DQ  = (const float*)d_in[8];
    const float* W_UQ  = (const float*)d_in[9];
    const float* b_UQ  = (const float*)d_in[10];
    const float* W_KR  = (const float*)d_in[11];
    const float* b_KR  = (const float*)d_in[12];
    const float* W_O   = (const float*)d_in[13];
    const float* b_O   = (const float*)d_in[14];

    float* out   = (float*)d_out;             // (4096, 2048)  output 0, fp32
    float* cKV_f = out + (size_t)8388608;     // (4096, 512)   output 1
    float* krc_f = out + (size_t)10485760;    // (4096, 2048)  output 2

    // out-proper (33.5 MB) is dead until the final GEMM -> park qC + qR
    // there; both consumed by mla_attn before the final GEMM overwrites.
    bf16* qC = (bf16*)d_out;                  // (B*S, H*128)
    bf16* qR = (bf16*)d_out + 8388608;        // (B*S, H*128)

    // ws (bf16 elements), lifetimes:
    //  hb    @0        8.4M  cast -> batch1; then reused as kR
    //  cKVb  @8.4M     2.1M  batch1 -> batch45
    //  cQ    @10.5M    6.3M  batch1 -> gemm_q
    //  WtAll @16.8M    8.4M  tc3 -> b1; tc2 -> b45; tcUQ -> q; then vT; tcWO
    //  kC    @25.2M    8.4M  batch45 -> attn
    //  vC    @33.6M    8.4M  batch45 -> transpose_v; then ctx (attn -> final)
    bf16* ws    = (bf16*)d_ws;
    bf16* hb    = ws + 0;
    bf16* cKVb  = ws + 8388608;
    bf16* cQ    = ws + 10485760;
    bf16* WtAll = ws + 16777216;
    bf16* kC    = ws + 25165824;
    bf16* vC    = ws + 33554432;
    bf16* kR    = hb;              // hb dead after batch1
    bf16* vT    = WtAll;           // WtAll free between gemm_q and tc(WO)
    bf16* ctx   = vC;              // vC dead after transpose_v

    dim3 tb(32, 8);

    cast_to_bf16<<<8192, 256, 0, stream>>>(h, hb, 8388608);

    // WtAll rows: [0,512)=W_DKV^T, [512,2560)=W_KR^T, [2560,4096)=W_DQ^T
    transpose_cast<<<dim3(16, 64), tb, 0, stream>>>(W_DKV, WtAll,           2048, 512);
    transpose_cast<<<dim3(64, 64), tb, 0, stream>>>(W_KR,  WtAll + 1048576, 2048, 2048);
    transpose_cast<<<dim3(48, 64), tb, 0, stream>>>(W_DQ,  WtAll + 5242880, 2048, 1536);

    gemm_batch1<<<dim3(32, 32), 256, 0, stream>>>(hb, WtAll, b_DKV, b_KR, b_DQ,
                                                  cKV_f, cKVb, krc_f, cQ);
    // hb dead from here
    rope_heads_f<<<16384, 256, 0, stream>>>(krc_f, kR);

    // Wt45 rows: [0,2048)=W_UK^T, [2048,4096)=W_UV^T (K=512)
    transpose_cast<<<dim3(64, 16), tb, 0, stream>>>(W_UK, WtAll,           512, 2048);
    transpose_cast<<<dim3(64, 16), tb, 0, stream>>>(W_UV, WtAll + 1048576, 512, 2048);
    gemm_batch45<<<dim3(32, 32), 256, 0, stream>>>(cKVb, WtAll, b_UK, b_UV, kC, vC);

    transpose_cast<<<dim3(64, 48), tb, 0, stream>>>(W_UQ, WtAll, 1536, 2048);
    gemm_q_rope<<<dim3(16, 32), 256, 0, stream>>>(cQ, WtAll, b_UQ, qC, qR);

    transpose_v<<<dim3(64, 4, 32), tb, 0, stream>>>(vC, vT);   // vC consumed

    mla_attn<<<dim3(32, 16), 512, 0, stream>>>(qC, qR, kC, kR, vT, ctx);

    transpose_cast<<<dim3(64, 64), tb, 0, stream>>>(W_O, WtAll, 2048, 2048);
    gemm_bt<<<dim3(16, 32), 256, 0, stream>>>(ctx, WtAll, b_O, out, nullptr, 4096, 2048, 2048);
}

// Round 11
// 536.327 us; speedup vs baseline: 1.0796x; 1.0029x over previous
//
#include <hip/hip_runtime.h>
#include <cstdint>
#include <cstddef>

typedef __bf16 bf16;
typedef __bf16 bf16x8 __attribute__((ext_vector_type(8)));
typedef float  f32x4  __attribute__((ext_vector_type(4)));

#define INVF_C 0.20762050593046014f   // log2(10000)/64

// global -> LDS async copy, 16B per lane. LDS base must be wave-uniform;
// HW scatters lane i at base + 16*i. (m97-verified pattern.)
__device__ __forceinline__ void async_copy16(const void* g, void* l)
{
    auto gp = (__attribute__((address_space(1))) const void*)(reinterpret_cast<uintptr_t>(g));
    auto lp = (__attribute__((address_space(3))) void*)(uint32_t)(reinterpret_cast<uintptr_t>(l));
    __builtin_amdgcn_global_load_lds(gp, lp, 16, 0, 0);
}

// ---------------------------------------------------------------------------
// elementwise fp32 -> bf16 cast, 4 elems/thread, n % 4 == 0
// ---------------------------------------------------------------------------
__global__ void cast_to_bf16(const float* __restrict__ in, bf16* __restrict__ out, int n)
{
    const int i = (blockIdx.x * 256 + threadIdx.x) * 4;
    if (i < n) {
        const float4 v = *(const float4*)(in + i);
        out[i]     = (bf16)v.x;
        out[i + 1] = (bf16)v.y;
        out[i + 2] = (bf16)v.z;
        out[i + 3] = (bf16)v.w;
    }
}

// ---------------------------------------------------------------------------
// fused transpose + cast: out[c*R + r] = (bf16)in[r*C + c]; in is RxC fp32.
// grid (C/32, R/32), block (32,8).
// ---------------------------------------------------------------------------
__global__ void transpose_cast(const float* __restrict__ in, bf16* __restrict__ out,
                               int R, int Ccols)
{
    __shared__ float tile[32][33];
    const int c0 = blockIdx.x * 32;
    const int r0 = blockIdx.y * 32;
    const int tx = threadIdx.x, ty = threadIdx.y;
    for (int i = ty; i < 32; i += 8)
        tile[i][tx] = in[(size_t)(r0 + i) * Ccols + c0 + tx];
    __syncthreads();
    for (int i = ty; i < 32; i += 8)
        out[(size_t)(c0 + i) * R + r0 + tx] = (bf16)tile[tx][i];
}

// ---------------------------------------------------------------------------
// Shared GEMM main loop (m97 structure): 128x128 tile, BK=64, 4 waves 2x2,
// global_load_lds width-16 staging into unpadded LDS. Verified rounds 0-10.
// No XCD swizzle: operands are L3-resident (round-5 regression; m160).
// ---------------------------------------------------------------------------
__device__ __forceinline__ void gemm_core(const bf16* __restrict__ A,
                                          const bf16* __restrict__ Bt,
                                          int K, int m0, int n0,
                                          bf16* As, bf16* Bs,
                                          f32x4 (&acc)[4][4])
{
    const int tid  = threadIdx.x;
    const int wave = tid >> 6;
    const int lane = tid & 63;
    const int quad = lane >> 4;
    const int l15  = lane & 15;
    const int wm   = (wave >> 1) * 64;
    const int wn   = (wave & 1) * 64;

    // staging: wave w covers rows [w*32, w*32+32) in 4 issues of 8 rows;
    // lane l -> row l>>3, col chunk (l&7)*8 (matches lane*16B LDS scatter)
    const int srow = lane >> 3;
    const int scol = (lane & 7) * 8;
    const bf16* Ab = A  + (size_t)(m0 + wave * 32 + srow) * K + scol;
    const bf16* Bb = Bt + (size_t)(n0 + wave * 32 + srow) * K + scol;
    bf16* AsW = &As[(wave * 32) * 64];
    bf16* BsW = &Bs[(wave * 32) * 64];

    for (int k0 = 0; k0 < K; k0 += 64) {
        __syncthreads();   // previous tile fully consumed
#pragma unroll
        for (int i = 0; i < 4; ++i) {
            async_copy16(Ab + (size_t)(i * 8) * K + k0, AsW + i * 8 * 64);
            async_copy16(Bb + (size_t)(i * 8) * K + k0, BsW + i * 8 * 64);
        }
        __syncthreads();   // drains vmcnt(0) -> staged data visible
#pragma unroll
        for (int ks = 0; ks < 2; ++ks) {
            bf16x8 af[4], bfr[4];
#pragma unroll
            for (int i = 0; i < 4; ++i)
                af[i] = *(const bf16x8*)&As[(wm + i * 16 + l15) * 64 + ks * 32 + quad * 8];
#pragma unroll
            for (int j = 0; j < 4; ++j)
                bfr[j] = *(const bf16x8*)&Bs[(wn + j * 16 + l15) * 64 + ks * 32 + quad * 8];
#pragma unroll
            for (int i = 0; i < 4; ++i)
#pragma unroll
                for (int j = 0; j < 4; ++j)
                    acc[i][j] = __builtin_amdgcn_mfma_f32_16x16x32_bf16(af[i], bfr[j], acc[i][j], 0, 0, 0);
        }
    }
}

// ---------------------------------------------------------------------------
// Generic C[M,N] = A @ Bt^T + bias; dual fp32/bf16 epilogue (final GEMM).
// ---------------------------------------------------------------------------
__global__ __launch_bounds__(256, 2)
void gemm_bt(const bf16* __restrict__ A, const bf16* __restrict__ Bt,
             const float* __restrict__ bias, float* __restrict__ C,
             bf16* __restrict__ Cb, int M, int N, int K)
{
    __shared__ bf16 As[128 * 64];
    __shared__ bf16 Bs[128 * 64];
    const int m0 = blockIdx.y * 128;
    const int n0 = blockIdx.x * 128;
    f32x4 acc[4][4] = {};
    gemm_core(A, Bt, K, m0, n0, As, Bs, acc);

    const int tid  = threadIdx.x;
    const int wave = tid >> 6;
    const int lane = tid & 63;
    const int quad = lane >> 4;
    const int l15  = lane & 15;
    const int wm   = (wave >> 1) * 64;
    const int wn   = (wave & 1) * 64;

    // C/D layout: col = lane&15, row = quad*4 + r (verified m89/m91)
#pragma unroll
    for (int j = 0; j < 4; ++j) {
        const int col = n0 + wn + j * 16 + l15;
        const float bv = bias[col];
#pragma unroll
        for (int i = 0; i < 4; ++i) {
            const int row = m0 + wm + i * 16 + quad * 4;
#pragma unroll
            for (int r = 0; r < 4; ++r) {
                const float v = acc[i][j][r] + bv;
                if (C)  C [(size_t)(row + r) * N + col] = v;
                if (Cb) Cb[(size_t)(row + r) * N + col] = (bf16)v;
            }
        }
    }
}

// ---------------------------------------------------------------------------
// Batched GEMM #1: A=hb (4096x2048), B = [W_DKV^T | W_KR^T | W_DQ^T]
// stacked as WtAll (4096 x 2048). N=4096 -> 1024 blocks (full device).
// Section epilogues: cols [0,512) -> cKV fp32+bf16; [512,2560) -> krc fp32;
// [2560,4096) -> cQ bf16. Section boundaries are multiples of 128.
// ---------------------------------------------------------------------------
__global__ __launch_bounds__(256, 2)
void gemm_batch1(const bf16* __restrict__ A, const bf16* __restrict__ WtAll,
                 const float* __restrict__ bDKV, const float* __restrict__ bKR,
                 const float* __restrict__ bDQ,
                 float* __restrict__ cKV_f, bf16* __restrict__ cKVb,
                 float* __restrict__ krc_f, bf16* __restrict__ cQ)
{
    __shared__ bf16 As[128 * 64];
    __shared__ bf16 Bs[128 * 64];
    const int m0 = blockIdx.y * 128;
    const int n0 = blockIdx.x * 128;
    f32x4 acc[4][4] = {};
    gemm_core(A, WtAll, 2048, m0, n0, As, Bs, acc);

    const int tid  = threadIdx.x;
    const int wave = tid >> 6;
    const int lane = tid & 63;
    const int quad = lane >> 4;
    const int l15  = lane & 15;
    const int wm   = (wave >> 1) * 64;
    const int wn   = (wave & 1) * 64;

    if (n0 < 512) {
#pragma unroll
        for (int j = 0; j < 4; ++j) {
            const int col = n0 + wn + j * 16 + l15;
            const float bv = bDKV[col];
#pragma unroll
            for (int i = 0; i < 4; ++i) {
                const int row = m0 + wm + i * 16 + quad * 4;
#pragma unroll
                for (int r = 0; r < 4; ++r) {
                    const float v = acc[i][j][r] + bv;
                    cKV_f[(size_t)(row + r) * 512 + col] = v;
                    cKVb [(size_t)(row + r) * 512 + col] = (bf16)v;
                }
            }
        }
    } else if (n0 < 2560) {
#pragma unroll
        for (int j = 0; j < 4; ++j) {
            const int col = n0 + wn + j * 16 + l15;
            const int cl  = col - 512;
            const float bv = bKR[cl];
#pragma unroll
            for (int i = 0; i < 4; ++i) {
                const int row = m0 + wm + i * 16 + quad * 4;
#pragma unroll
                for (int r = 0; r < 4; ++r)
                    krc_f[(size_t)(row + r) * 2048 + cl] = acc[i][j][r] + bv;
            }
        }
    } else {
#pragma unroll
        for (int j = 0; j < 4; ++j) {
            const int col = n0 + wn + j * 16 + l15;
            const int cl  = col - 2560;
            const float bv = bDQ[cl];
#pragma unroll
            for (int i = 0; i < 4; ++i) {
                const int row = m0 + wm + i * 16 + quad * 4;
#pragma unroll
                for (int r = 0; r < 4; ++r)
                    cQ[(size_t)(row + r) * 1536 + cl] = (bf16)(acc[i][j][r] + bv);
            }
        }
    }
}

// ---------------------------------------------------------------------------
// Batched GEMM #4+5: A=cKVb (4096x512), B = [W_UK^T | W_UV^T] (4096x512).
// Cols [0,2048) -> kC; [2048,4096) -> vC. Both bf16.
// ---------------------------------------------------------------------------
__global__ __launch_bounds__(256, 2)
void gemm_batch45(const bf16* __restrict__ A, const bf16* __restrict__ Wt45,
                  const float* __restrict__ bUK, const float* __restrict__ bUV,
                  bf16* __restrict__ kC, bf16* __restrict__ vC)
{
    __shared__ bf16 As[128 * 64];
    __shared__ bf16 Bs[128 * 64];
    const int m0 = blockIdx.y * 128;
    const int n0 = blockIdx.x * 128;
    f32x4 acc[4][4] = {};
    gemm_core(A, Wt45, 512, m0, n0, As, Bs, acc);

    const int tid  = threadIdx.x;
    const int wave = tid >> 6;
    const int lane = tid & 63;
    const int quad = lane >> 4;
    const int l15  = lane & 15;
    const int wm   = (wave >> 1) * 64;
    const int wn   = (wave & 1) * 64;

    const bool isK = (n0 < 2048);
    bf16* outp = isK ? kC : vC;
    const float* bp = isK ? bUK : bUV;
    const int base = isK ? 0 : 2048;
#pragma unroll
    for (int j = 0; j < 4; ++j) {
        const int col = n0 + wn + j * 16 + l15;
        const int cl  = col - base;
        const float bv = bp[cl];
#pragma unroll
        for (int i = 0; i < 4; ++i) {
            const int row = m0 + wm + i * 16 + quad * 4;
#pragma unroll
            for (int r = 0; r < 4; ++r)
                outp[(size_t)(row + r) * 2048 + cl] = (bf16)(acc[i][j][r] + bv);
        }
    }
}

// ---------------------------------------------------------------------------
// qC GEMM with fused RoPE epilogue: writes qC = (A@Wt+b)*2^-4 (bf16) AND
// qR = rope(A@Wt+b)*2^-4 (bf16). PRE-SCALED by 1/sqrt(256) = 0.0625 (round
// 11): power-of-2 scale is exact in bf16 (exponent shift), rope is linear
// so scale commutes, and MFMA over uniformly 2^-4-scaled operands is
// bit-identical to scaling the scores afterward -> attn drops 16 v_mul/tile.
// __sincosf (hw v_sin/v_cos): sincosf's Payne-Hanek slow path used scratch
// -> 845 MB WRITE_SIZE (round-3 post-mortem). Angle err ~2e-4 rad << bf16.
// ---------------------------------------------------------------------------
__global__ __launch_bounds__(256, 2)
void gemm_q_rope(const bf16* __restrict__ A, const bf16* __restrict__ Bt,
                 const float* __restrict__ bias,
                 bf16* __restrict__ qC, bf16* __restrict__ qR)
{
    __shared__ bf16 As[128 * 64];
    __shared__ bf16 Bs[128 * 64];
    const int m0 = blockIdx.y * 128;
    const int n0 = blockIdx.x * 128;
    f32x4 acc[4][4] = {};
    gemm_core(A, Bt, 1536, m0, n0, As, Bs, acc);

    const int tid  = threadIdx.x;
    const int wave = tid >> 6;
    const int lane = tid & 63;
    const int quad = lane >> 4;
    const int l15  = lane & 15;
    const int wm   = (wave >> 1) * 64;
    const int wn   = (wave & 1) * 64;
    const int odd  = l15 & 1;

#pragma unroll
    for (int j = 0; j < 4; ++j) {
        const int col = n0 + wn + j * 16 + l15;
        const float bv = bias[col];
        const float freq = exp2f(-(float)((col & 127) >> 1) * INVF_C);
#pragma unroll
        for (int i = 0; i < 4; ++i) {
            const int rowb = m0 + wm + i * 16 + quad * 4;
#pragma unroll
            for (int r = 0; r < 4; ++r) {
                const int row = rowb + r;
                const float v = acc[i][j][r] + bv;
                qC[(size_t)row * 2048 + col] = (bf16)(v * 0.0625f);
                const float vp = __shfl_xor(v, 1, 64);
                const float x1 = odd ? vp : v;
                const float x2 = odd ? v  : vp;
                const float ang = (float)(row & 2047) * freq;
                float sn, cs;
                __sincosf(ang, &sn, &cs);
                const float res = odd ? (x1 * sn + x2 * cs) : (x1 * cs - x2 * sn);
                qR[(size_t)row * 2048 + col] = (bf16)(res * 0.0625f);
            }
        }
    }
}

// vC (B*S, H*128) bf16 -> vT (B*H, 128, S). grid (S/32, 128/32, 32), block (32,8)
__global__ void transpose_v(const bf16* __restrict__ vC, bf16* __restrict__ vT)
{
    __shared__ bf16 tile[32][33];
    const int bh = blockIdx.z, b = bh >> 4, h = bh & 15;
    const int s0 = blockIdx.x * 32, d0 = blockIdx.y * 32;
    const int tx = threadIdx.x, ty = threadIdx.y;
    for (int i = ty; i < 32; i += 8)
        tile[i][tx] = vC[((size_t)(b * 2048 + s0 + i)) * 2048 + h * 128 + d0 + tx];
    __syncthreads();
    for (int i = ty; i < 32; i += 8)
        vT[((size_t)(bh * 128 + d0 + i)) * 2048 + s0 + tx] = tile[tx][i];
}

// ---------------------------------------------------------------------------
// per-head interleaved RoPE (kR path), layout (B*S, H*128), fp32 input.
// __sincosf: no scratch slow path (round-3 post-mortem).
// ---------------------------------------------------------------------------
__global__ void rope_heads_f(const float* __restrict__ in, bf16* __restrict__ out)
{
    const int idx = blockIdx.x * 256 + threadIdx.x;     // 2*2048*16*64 total
    const int j = idx & 63;
    const int h = (idx >> 6) & 15;
    const int s = (idx >> 10) & 2047;
    const int b = idx >> 21;
    const size_t src = ((size_t)(b * 2048 + s)) * 2048 + h * 128 + 2 * j;
    const float x1 = in[src], x2 = in[src + 1];
    const float ang = (float)s * exp2f(-(float)j * INVF_C);
    float sn, cs;
    __sincosf(ang, &sn, &cs);
    out[src]     = (bf16)(x1 * cs - x2 * sn);
    out[src + 1] = (bf16)(x1 * sn + x2 * cs);
}

// ---------------------------------------------------------------------------
// Flash attention, causal. Split operands, all bf16:
//   qC,qR (PRE-SCALED by 2^-4), kC,kR : (B*S, H*128);  Vt : (B*H, 128, S).
// BQ=128 (8 waves x 16 q-rows, wave-local softmax), BKV=64.
// Grid (bh=32, y=16): 512 blocks, 2/CU -> all co-resident.
// Balance remap: co-resident pair (y, y+8) -> q-tiles (2y, 15-2y) -> constant
// 34 KV-tile-units per CU (verified round 2: 159 -> 138 us).
// launch_bounds(512,2): 2 blocks/CU; (512,4) spilled (round-1 post-mortem).
// No setprio / no defer-max (regressed round 5; 8-wave lockstep = m190 null).
// No split-wave symmetric tiles (round-9: +44% staging iterations, 174 us).
// T14 async-stage verified round 6 (134 -> 127 us, VGPR 84, no spill).
// Round-11: scores arrive pre-scaled (no 0.0625 mul); diag mask runs under a
// wave-uniform branch -> non-diag tiles' softmax prologue is 16 bare fmax.
// LDS: Ks 64x264 + Vs 128x72 + Ps 128x72 = 70656 B.
// ---------------------------------------------------------------------------
__global__ __launch_bounds__(512, 2)
void mla_attn(const bf16* __restrict__ qCp, const bf16* __restrict__ qRp,
              const bf16* __restrict__ kCp, const bf16* __restrict__ kRp,
              const bf16* __restrict__ Vt, bf16* __restrict__ ctx)
{
    __shared__ bf16 Ks[64 * 264];
    __shared__ bf16 Vs[128 * 72];
    __shared__ bf16 Ps[128 * 72];
    const int bh   = blockIdx.x;
    const int b    = bh >> 4, hh = bh & 15;
    const int yq   = blockIdx.y;
    const int qt   = (yq < 8) ? (2 * yq) : (31 - 2 * yq);   // balance remap
    const int q0   = qt * 128;
    const int tid  = threadIdx.x;
    const int wave = tid >> 6;
    const int lane = tid & 63;
    const int quad = lane >> 4;
    const int l15  = lane & 15;
    const int wq   = q0 + wave * 16;       // wave's first q row

    // Q fragments resident (A-operand: m=lane&15, k=quad*8+j).
    bf16x8 qf[8];
    {
        const size_t qoff = ((size_t)(b * 2048 + wq + l15)) * 2048
                          + hh * 128 + quad * 8;
#pragma unroll
        for (int ks = 0; ks < 4; ++ks) {
            qf[ks]     = *(const bf16x8*)(qCp + qoff + ks * 32);
            qf[4 + ks] = *(const bf16x8*)(qRp + qoff + ks * 32);
        }
    }

    float mstate[4], lstate[4];
    f32x4 o[8];
#pragma unroll
    for (int r = 0; r < 4; ++r) { mstate[r] = -1e30f; lstate[r] = 0.0f; }
#pragma unroll
    for (int dt = 0; dt < 8; ++dt) { f32x4 z = {0.f, 0.f, 0.f, 0.f}; o[dt] = z; }

    const int krow = tid >> 4, kcol = (tid & 15) * 8;   // K staging (512 thr)
    const int vsr  = tid >> 3, vsc  = (tid & 7) * 8;    // V staging

    // T14 staging registers (6 x bf16x8 = 24 VGPR)
    bf16x8 stKC[2], stKR[2], stV[2];

    const int ntiles = 2 * qt + 2;

    // prologue: load tile 0 into regs, write LDS, sync
    {
#pragma unroll
        for (int it = 0; it < 2; ++it) {
            const int row = it * 32 + krow;
            const size_t g = ((size_t)(b * 2048 + row)) * 2048 + hh * 128 + kcol;
            stKC[it] = *(const bf16x8*)(kCp + g);
            stKR[it] = *(const bf16x8*)(kRp + g);
        }
#pragma unroll
        for (int it = 0; it < 2; ++it) {
            const int d = it * 64 + vsr;
            stV[it] = *(const bf16x8*)(Vt + ((size_t)(bh * 128 + d)) * 2048 + vsc);
        }
#pragma unroll
        for (int it = 0; it < 2; ++it) {
            const int row = it * 32 + krow;
            *(bf16x8*)&Ks[row * 264 + kcol]       = stKC[it];
            *(bf16x8*)&Ks[row * 264 + 128 + kcol] = stKR[it];
        }
#pragma unroll
        for (int it = 0; it < 2; ++it) {
            const int d = it * 64 + vsr;
            *(bf16x8*)&Vs[d * 72 + vsc] = stV[it];
        }
    }
    __syncthreads();

    for (int t = 0; t < ntiles; ++t) {
        const int kk0 = t * 64;

        // T14: issue next tile's global loads; latency hides under compute(t)
        if (t + 1 < ntiles) {
            const int nk0 = kk0 + 64;
#pragma unroll
            for (int it = 0; it < 2; ++it) {
                const int row = it * 32 + krow;
                const size_t g = ((size_t)(b * 2048 + nk0 + row)) * 2048 + hh * 128 + kcol;
                stKC[it] = *(const bf16x8*)(kCp + g);
                stKR[it] = *(const bf16x8*)(kRp + g);
            }
#pragma unroll
            for (int it = 0; it < 2; ++it) {
                const int d = it * 64 + vsr;
                stV[it] = *(const bf16x8*)(Vt + ((size_t)(bh * 128 + d)) * 2048 + nk0 + vsc);
            }
        }

        if (kk0 <= wq + 15) {   // wave-uniform: tile not fully masked
            f32x4 sc[4] = {};
#pragma unroll
            for (int ks = 0; ks < 8; ++ks)
#pragma unroll
                for (int j = 0; j < 4; ++j) {
                    bf16x8 kf = *(const bf16x8*)&Ks[(j * 16 + l15) * 264 + ks * 32 + quad * 8];
                    sc[j] = __builtin_amdgcn_mfma_f32_16x16x32_bf16(qf[ks], kf, sc[j], 0, 0, 0);
                }

            // scores are pre-scaled (q carries 2^-4); only diag tiles mask.
            const bool diag = (kk0 + 63 > wq);   // wave-uniform branch
            float rowmax[4] = {-1e30f, -1e30f, -1e30f, -1e30f};
            if (diag) {
#pragma unroll
                for (int j = 0; j < 4; ++j) {
                    const int kkcol = kk0 + j * 16 + l15;
#pragma unroll
                    for (int r = 0; r < 4; ++r) {
                        float s = sc[j][r];
                        if (kkcol > wq + quad * 4 + r) s = -1e30f;
                        sc[j][r] = s;
                        rowmax[r] = fmaxf(rowmax[r], s);
                    }
                }
            } else {
#pragma unroll
                for (int j = 0; j < 4; ++j)
#pragma unroll
                    for (int r = 0; r < 4; ++r)
                        rowmax[r] = fmaxf(rowmax[r], sc[j][r]);
            }
#pragma unroll
            for (int r = 0; r < 4; ++r) {  // reduce across the 16 col-lanes
                float v = rowmax[r];
                v = fmaxf(v, __shfl_xor(v, 1, 64));
                v = fmaxf(v, __shfl_xor(v, 2, 64));
                v = fmaxf(v, __shfl_xor(v, 4, 64));
                v = fmaxf(v, __shfl_xor(v, 8, 64));
                rowmax[r] = v;
            }
            float alpha[4];
#pragma unroll
            for (int r = 0; r < 4; ++r) {
                const float mnew = fmaxf(mstate[r], rowmax[r]);
                alpha[r] = __expf(mstate[r] - mnew);
                mstate[r] = mnew;
            }
            float rowsum[4] = {0.f, 0.f, 0.f, 0.f};
#pragma unroll
            for (int j = 0; j < 4; ++j)
#pragma unroll
                for (int r = 0; r < 4; ++r) {
                    const float p = __expf(sc[j][r] - mstate[r]);
                    sc[j][r] = p;
                    rowsum[r] += p;
                }
#pragma unroll
            for (int r = 0; r < 4; ++r) {
                float v = rowsum[r];
                v += __shfl_xor(v, 1, 64);
                v += __shfl_xor(v, 2, 64);
                v += __shfl_xor(v, 4, 64);
                v += __shfl_xor(v, 8, 64);
                lstate[r] = lstate[r] * alpha[r] + v;
            }
            // P: C-layout -> LDS -> A-operand layout (verified, m120)
#pragma unroll
            for (int j = 0; j < 4; ++j)
#pragma unroll
                for (int r = 0; r < 4; ++r)
                    Ps[(wave * 16 + quad * 4 + r) * 72 + j * 16 + l15] = (bf16)sc[j][r];
#pragma unroll
            for (int dt = 0; dt < 8; ++dt)
#pragma unroll
                for (int r = 0; r < 4; ++r)
                    o[dt][r] *= alpha[r];
#pragma unroll
            for (int ks2 = 0; ks2 < 2; ++ks2) {
                bf16x8 pf = *(const bf16x8*)&Ps[(wave * 16 + l15) * 72 + ks2 * 32 + quad * 8];
#pragma unroll
                for (int dt = 0; dt < 8; ++dt) {
                    bf16x8 vf = *(const bf16x8*)&Vs[(dt * 16 + l15) * 72 + ks2 * 32 + quad * 8];
                    o[dt] = __builtin_amdgcn_mfma_f32_16x16x32_bf16(pf, vf, o[dt], 0, 0, 0);
                }
            }
        }

        __syncthreads();   // everyone done reading Ks/Vs of tile t
        if (t + 1 < ntiles) {
            // T14: LDS write of the prefetched tile (vmcnt drained on use)
#pragma unroll
            for (int it = 0; it < 2; ++it) {
                const int row = it * 32 + krow;
                *(bf16x8*)&Ks[row * 264 + kcol]       = stKC[it];
                *(bf16x8*)&Ks[row * 264 + 128 + kcol] = stKR[it];
            }
#pragma unroll
            for (int it = 0; it < 2; ++it) {
                const int d = it * 64 + vsr;
                *(bf16x8*)&Vs[d * 72 + vsc] = stV[it];
            }
        }
        __syncthreads();   // staged data visible for tile t+1
    }

    float inv_l[4];
#pragma unroll
    for (int r = 0; r < 4; ++r) inv_l[r] = 1.0f / lstate[r];
#pragma unroll
    for (int dt = 0; dt < 8; ++dt) {
        const int d = dt * 16 + l15;
#pragma unroll
        for (int r = 0; r < 4; ++r) {
            const int q = wq + quad * 4 + r;
            ctx[((size_t)(b * 2048 + q)) * 2048 + hh * 128 + d] = (bf16)(o[dt][r] * inv_l[r]);
        }
    }
}

// ---------------------------------------------------------------------------
extern "C" void kernel_launch(void* const* d_in, const int* in_sizes, int n_in,
                              void* d_out, int out_size, void* d_ws, size_t ws_size,
                              hipStream_t stream)
{
    const float* h     = (const float*)d_in[0];
    const float* W_DKV = (const float*)d_in[1];
    const float* b_DKV = (const float*)d_in[2];
    const float* W_UK  = (const float*)d_in[3];
    const float* b_UK  = (const float*)d_in[4];
    const float* W_UV  = (const float*)d_in[5];
    const float* b_UV  = (const float*)d_in[6];
    const float* W_DQ  = (const float*)d_in[7];
    const float* b_DQ  = (const float*)d_in[8];
    const float* W_UQ  = (const float*)d_in[9];
    const float* b_UQ  = (const float*)d_in[10];
    const float* W_KR  = (const float*)d_in[11];
    const float* b_KR  = (const float*)d_in[12];
    const float* W_O   = (const float*)d_in[13];
    const float* b_O   = (const float*)d_in[14];

    float* out   = (float*)d_out;             // (4096, 2048)  output 0, fp32
    float* cKV_f = out + (size_t)8388608;     // (4096, 512)   output 1
    float* krc_f = out + (size_t)10485760;    // (4096, 2048)  output 2

    // out-proper (33.5 MB) is dead until the final GEMM -> park qC + qR
    // there; both consumed by mla_attn before the final GEMM overwrites.
    bf16* qC = (bf16*)d_out;                  // (B*S, H*128)
    bf16* qR = (bf16*)d_out + 8388608;        // (B*S, H*128)

    // ws (bf16 elements), lifetimes:
    //  hb    @0        8.4M  cast -> batch1; then reused as kR
    //  cKVb  @8.4M     2.1M  batch1 -> batch45
    //  cQ    @10.5M    6.3M  batch1 -> gemm_q
    //  WtAll @16.8M    8.4M  tc3 -> b1; tc2 -> b45; tcUQ -> q; then vT; tcWO
    //  kC    @25.2M    8.4M  batch45 -> attn
    //  vC    @33.6M    8.4M  batch45 -> transpose_v; then ctx (attn -> final)
    bf16* ws    = (bf16*)d_ws;
    bf16* hb    = ws + 0;
    bf16* cKVb  = ws + 8388608;
    bf16* cQ    = ws + 10485760;
    bf16* WtAll = ws + 16777216;
    bf16* kC    = ws + 25165824;
    bf16* vC    = ws + 33554432;
    bf16* kR    = hb;              // hb dead after batch1
    bf16* vT    = WtAll;           // WtAll free between gemm_q and tc(WO)
    bf16* ctx   = vC;              // vC dead after transpose_v

    dim3 tb(32, 8);

    cast_to_bf16<<<8192, 256, 0, stream>>>(h, hb, 8388608);

    // WtAll rows: [0,512)=W_DKV^T, [512,2560)=W_KR^T, [2560,4096)=W_DQ^T
    transpose_cast<<<dim3(16, 64), tb, 0, stream>>>(W_DKV, WtAll,           2048, 512);
    transpose_cast<<<dim3(64, 64), tb, 0, stream>>>(W_KR,  WtAll + 1048576, 2048, 2048);
    transpose_cast<<<dim3(48, 64), tb, 0, stream>>>(W_DQ,  WtAll + 5242880, 2048, 1536);

    gemm_batch1<<<dim3(32, 32), 256, 0, stream>>>(hb, WtAll, b_DKV, b_KR, b_DQ,
                                                  cKV_f, cKVb, krc_f, cQ);
    // hb dead from here
    rope_heads_f<<<16384, 256, 0, stream>>>(krc_f, kR);

    // Wt45 rows: [0,2048)=W_UK^T, [2048,4096)=W_UV^T (K=512)
    transpose_cast<<<dim3(64, 16), tb, 0, stream>>>(W_UK, WtAll,           512, 2048);
    transpose_cast<<<dim3(64, 16), tb, 0, stream>>>(W_UV, WtAll + 1048576, 512, 2048);
    gemm_batch45<<<dim3(32, 32), 256, 0, stream>>>(cKVb, WtAll, b_UK, b_UV, kC, vC);

    transpose_cast<<<dim3(64, 48), tb, 0, stream>>>(W_UQ, WtAll, 1536, 2048);
    gemm_q_rope<<<dim3(16, 32), 256, 0, stream>>>(cQ, WtAll, b_UQ, qC, qR);

    transpose_v<<<dim3(64, 4, 32), tb, 0, stream>>>(vC, vT);   // vC consumed

    mla_attn<<<dim3(32, 16), 512, 0, stream>>>(qC, qR, kC, kR, vT, ctx);

    transpose_cast<<<dim3(64, 64), tb, 0, stream>>>(W_O, WtAll, 2048, 2048);
    gemm_bt<<<dim3(16, 32), 256, 0, stream>>>(ctx, WtAll, b_O, out, nullptr, 4096, 2048, 2048);
}

// Round 12
// 523.123 us; speedup vs baseline: 1.1069x; 1.0252x over previous
//
#include <hip/hip_runtime.h>
#include <cstdint>
#include <cstddef>

typedef __bf16 bf16;
typedef __bf16 bf16x2 __attribute__((ext_vector_type(2)));
typedef __bf16 bf16x8 __attribute__((ext_vector_type(8)));
typedef float  f32x4  __attribute__((ext_vector_type(4)));

#define INVF_C 0.20762050593046014f   // log2(10000)/64

// global -> LDS async copy, 16B per lane. LDS base must be wave-uniform;
// HW scatters lane i at base + 16*i. (m97-verified pattern.)
__device__ __forceinline__ void async_copy16(const void* g, void* l)
{
    auto gp = (__attribute__((address_space(1))) const void*)(reinterpret_cast<uintptr_t>(g));
    auto lp = (__attribute__((address_space(3))) void*)(uint32_t)(reinterpret_cast<uintptr_t>(l));
    __builtin_amdgcn_global_load_lds(gp, lp, 16, 0, 0);
}

// ---------------------------------------------------------------------------
// elementwise fp32 -> bf16 cast, 4 elems/thread, n % 4 == 0
// ---------------------------------------------------------------------------
__global__ void cast_to_bf16(const float* __restrict__ in, bf16* __restrict__ out, int n)
{
    const int i = (blockIdx.x * 256 + threadIdx.x) * 4;
    if (i < n) {
        const float4 v = *(const float4*)(in + i);
        out[i]     = (bf16)v.x;
        out[i + 1] = (bf16)v.y;
        out[i + 2] = (bf16)v.z;
        out[i + 3] = (bf16)v.w;
    }
}

// ---------------------------------------------------------------------------
// fused transpose + cast: out[c*R + r] = (bf16)in[r*C + c]; in is RxC fp32.
// Round-12 isolated change: 64x64 tile, 256 threads, float4 loads
// (256B/wave-row) + bf16x2 stores (128B/wave vs scalar 64B half-width).
// R, C multiples of 64. grid (C/64, R/64). LDS store-side reads are 2-way
// (free, m136); load-side conflict-free. Same math as the 32x32 version
// (passed in round-5's composite; isolated here).
// ---------------------------------------------------------------------------
__global__ __launch_bounds__(256)
void transpose_cast(const float* __restrict__ in, bf16* __restrict__ out,
                    int R, int Ccols)
{
    __shared__ float tile[64][65];
    const int c0 = blockIdx.x * 64;
    const int r0 = blockIdx.y * 64;
    const int tid = threadIdx.x;
    const int lr = tid >> 4;
    const int lc = (tid & 15) * 4;
#pragma unroll
    for (int i = 0; i < 4; ++i) {
        const int row = i * 16 + lr;
        const float4 v = *(const float4*)(in + (size_t)(r0 + row) * Ccols + c0 + lc);
        tile[row][lc]     = v.x;
        tile[row][lc + 1] = v.y;
        tile[row][lc + 2] = v.z;
        tile[row][lc + 3] = v.w;
    }
    __syncthreads();
    const int rr  = (tid & 31) * 2;
    const int cc0 = tid >> 5;
#pragma unroll
    for (int i = 0; i < 8; ++i) {
        const int cc = i * 8 + cc0;
        bf16x2 p = { (bf16)tile[rr][cc], (bf16)tile[rr + 1][cc] };
        *(bf16x2*)(out + (size_t)(c0 + cc) * R + r0 + rr) = p;
    }
}

// ---------------------------------------------------------------------------
// Shared GEMM main loop (m97 structure): 128x128 tile, BK=64, 4 waves 2x2,
// global_load_lds width-16 staging into unpadded LDS. Verified rounds 0-11.
// No XCD swizzle: operands are L3-resident (round-5 regression; m160).
// ---------------------------------------------------------------------------
__device__ __forceinline__ void gemm_core(const bf16* __restrict__ A,
                                          const bf16* __restrict__ Bt,
                                          int K, int m0, int n0,
                                          bf16* As, bf16* Bs,
                                          f32x4 (&acc)[4][4])
{
    const int tid  = threadIdx.x;
    const int wave = tid >> 6;
    const int lane = tid & 63;
    const int quad = lane >> 4;
    const int l15  = lane & 15;
    const int wm   = (wave >> 1) * 64;
    const int wn   = (wave & 1) * 64;

    // staging: wave w covers rows [w*32, w*32+32) in 4 issues of 8 rows;
    // lane l -> row l>>3, col chunk (l&7)*8 (matches lane*16B LDS scatter)
    const int srow = lane >> 3;
    const int scol = (lane & 7) * 8;
    const bf16* Ab = A  + (size_t)(m0 + wave * 32 + srow) * K + scol;
    const bf16* Bb = Bt + (size_t)(n0 + wave * 32 + srow) * K + scol;
    bf16* AsW = &As[(wave * 32) * 64];
    bf16* BsW = &Bs[(wave * 32) * 64];

    for (int k0 = 0; k0 < K; k0 += 64) {
        __syncthreads();   // previous tile fully consumed
#pragma unroll
        for (int i = 0; i < 4; ++i) {
            async_copy16(Ab + (size_t)(i * 8) * K + k0, AsW + i * 8 * 64);
            async_copy16(Bb + (size_t)(i * 8) * K + k0, BsW + i * 8 * 64);
        }
        __syncthreads();   // drains vmcnt(0) -> staged data visible
#pragma unroll
        for (int ks = 0; ks < 2; ++ks) {
            bf16x8 af[4], bfr[4];
#pragma unroll
            for (int i = 0; i < 4; ++i)
                af[i] = *(const bf16x8*)&As[(wm + i * 16 + l15) * 64 + ks * 32 + quad * 8];
#pragma unroll
            for (int j = 0; j < 4; ++j)
                bfr[j] = *(const bf16x8*)&Bs[(wn + j * 16 + l15) * 64 + ks * 32 + quad * 8];
#pragma unroll
            for (int i = 0; i < 4; ++i)
#pragma unroll
                for (int j = 0; j < 4; ++j)
                    acc[i][j] = __builtin_amdgcn_mfma_f32_16x16x32_bf16(af[i], bfr[j], acc[i][j], 0, 0, 0);
        }
    }
}

// ---------------------------------------------------------------------------
// Generic C[M,N] = A @ Bt^T + bias; dual fp32/bf16 epilogue (final GEMM).
// ---------------------------------------------------------------------------
__global__ __launch_bounds__(256, 2)
void gemm_bt(const bf16* __restrict__ A, const bf16* __restrict__ Bt,
             const float* __restrict__ bias, float* __restrict__ C,
             bf16* __restrict__ Cb, int M, int N, int K)
{
    __shared__ bf16 As[128 * 64];
    __shared__ bf16 Bs[128 * 64];
    const int m0 = blockIdx.y * 128;
    const int n0 = blockIdx.x * 128;
    f32x4 acc[4][4] = {};
    gemm_core(A, Bt, K, m0, n0, As, Bs, acc);

    const int tid  = threadIdx.x;
    const int wave = tid >> 6;
    const int lane = tid & 63;
    const int quad = lane >> 4;
    const int l15  = lane & 15;
    const int wm   = (wave >> 1) * 64;
    const int wn   = (wave & 1) * 64;

    // C/D layout: col = lane&15, row = quad*4 + r (verified m89/m91)
#pragma unroll
    for (int j = 0; j < 4; ++j) {
        const int col = n0 + wn + j * 16 + l15;
        const float bv = bias[col];
#pragma unroll
        for (int i = 0; i < 4; ++i) {
            const int row = m0 + wm + i * 16 + quad * 4;
#pragma unroll
            for (int r = 0; r < 4; ++r) {
                const float v = acc[i][j][r] + bv;
                if (C)  C [(size_t)(row + r) * N + col] = v;
                if (Cb) Cb[(size_t)(row + r) * N + col] = (bf16)v;
            }
        }
    }
}

// ---------------------------------------------------------------------------
// Batched GEMM #1: A=hb (4096x2048), B = [W_DKV^T | W_KR^T | W_DQ^T]
// stacked as WtAll (4096 x 2048). N=4096 -> 1024 blocks (full device).
// Section epilogues: cols [0,512) -> cKV fp32+bf16; [512,2560) -> krc fp32;
// [2560,4096) -> cQ bf16. Section boundaries are multiples of 128.
// ---------------------------------------------------------------------------
__global__ __launch_bounds__(256, 2)
void gemm_batch1(const bf16* __restrict__ A, const bf16* __restrict__ WtAll,
                 const float* __restrict__ bDKV, const float* __restrict__ bKR,
                 const float* __restrict__ bDQ,
                 float* __restrict__ cKV_f, bf16* __restrict__ cKVb,
                 float* __restrict__ krc_f, bf16* __restrict__ cQ)
{
    __shared__ bf16 As[128 * 64];
    __shared__ bf16 Bs[128 * 64];
    const int m0 = blockIdx.y * 128;
    const int n0 = blockIdx.x * 128;
    f32x4 acc[4][4] = {};
    gemm_core(A, WtAll, 2048, m0, n0, As, Bs, acc);

    const int tid  = threadIdx.x;
    const int wave = tid >> 6;
    const int lane = tid & 63;
    const int quad = lane >> 4;
    const int l15  = lane & 15;
    const int wm   = (wave >> 1) * 64;
    const int wn   = (wave & 1) * 64;

    if (n0 < 512) {
#pragma unroll
        for (int j = 0; j < 4; ++j) {
            const int col = n0 + wn + j * 16 + l15;
            const float bv = bDKV[col];
#pragma unroll
            for (int i = 0; i < 4; ++i) {
                const int row = m0 + wm + i * 16 + quad * 4;
#pragma unroll
                for (int r = 0; r < 4; ++r) {
                    const float v = acc[i][j][r] + bv;
                    cKV_f[(size_t)(row + r) * 512 + col] = v;
                    cKVb [(size_t)(row + r) * 512 + col] = (bf16)v;
                }
            }
        }
    } else if (n0 < 2560) {
#pragma unroll
        for (int j = 0; j < 4; ++j) {
            const int col = n0 + wn + j * 16 + l15;
            const int cl  = col - 512;
            const float bv = bKR[cl];
#pragma unroll
            for (int i = 0; i < 4; ++i) {
                const int row = m0 + wm + i * 16 + quad * 4;
#pragma unroll
                for (int r = 0; r < 4; ++r)
                    krc_f[(size_t)(row + r) * 2048 + cl] = acc[i][j][r] + bv;
            }
        }
    } else {
#pragma unroll
        for (int j = 0; j < 4; ++j) {
            const int col = n0 + wn + j * 16 + l15;
            const int cl  = col - 2560;
            const float bv = bDQ[cl];
#pragma unroll
            for (int i = 0; i < 4; ++i) {
                const int row = m0 + wm + i * 16 + quad * 4;
#pragma unroll
                for (int r = 0; r < 4; ++r)
                    cQ[(size_t)(row + r) * 1536 + cl] = (bf16)(acc[i][j][r] + bv);
            }
        }
    }
}

// ---------------------------------------------------------------------------
// Batched GEMM #4+5: A=cKVb (4096x512), B = [W_UK^T | W_UV^T] (4096x512).
// Cols [0,2048) -> kC; [2048,4096) -> vC. Both bf16.
// ---------------------------------------------------------------------------
__global__ __launch_bounds__(256, 2)
void gemm_batch45(const bf16* __restrict__ A, const bf16* __restrict__ Wt45,
                  const float* __restrict__ bUK, const float* __restrict__ bUV,
                  bf16* __restrict__ kC, bf16* __restrict__ vC)
{
    __shared__ bf16 As[128 * 64];
    __shared__ bf16 Bs[128 * 64];
    const int m0 = blockIdx.y * 128;
    const int n0 = blockIdx.x * 128;
    f32x4 acc[4][4] = {};
    gemm_core(A, Wt45, 512, m0, n0, As, Bs, acc);

    const int tid  = threadIdx.x;
    const int wave = tid >> 6;
    const int lane = tid & 63;
    const int quad = lane >> 4;
    const int l15  = lane & 15;
    const int wm   = (wave >> 1) * 64;
    const int wn   = (wave & 1) * 64;

    const bool isK = (n0 < 2048);
    bf16* outp = isK ? kC : vC;
    const float* bp = isK ? bUK : bUV;
    const int base = isK ? 0 : 2048;
#pragma unroll
    for (int j = 0; j < 4; ++j) {
        const int col = n0 + wn + j * 16 + l15;
        const int cl  = col - base;
        const float bv = bp[cl];
#pragma unroll
        for (int i = 0; i < 4; ++i) {
            const int row = m0 + wm + i * 16 + quad * 4;
#pragma unroll
            for (int r = 0; r < 4; ++r)
                outp[(size_t)(row + r) * 2048 + cl] = (bf16)(acc[i][j][r] + bv);
        }
    }
}

// ---------------------------------------------------------------------------
// qC GEMM with fused RoPE epilogue: writes qC = (A@Wt+b)*2^-4 (bf16) AND
// qR = rope(A@Wt+b)*2^-4 (bf16). PRE-SCALED by 1/sqrt(256) = 0.0625 (round
// 11): power-of-2 scale is exact in bf16 (exponent shift), rope is linear
// so scale commutes, and MFMA over uniformly 2^-4-scaled operands is
// bit-identical to scaling the scores afterward -> attn drops 16 v_mul/tile.
// __sincosf (hw v_sin/v_cos): sincosf's Payne-Hanek slow path used scratch
// -> 845 MB WRITE_SIZE (round-3 post-mortem). Angle err ~2e-4 rad << bf16.
// ---------------------------------------------------------------------------
__global__ __launch_bounds__(256, 2)
void gemm_q_rope(const bf16* __restrict__ A, const bf16* __restrict__ Bt,
                 const float* __restrict__ bias,
                 bf16* __restrict__ qC, bf16* __restrict__ qR)
{
    __shared__ bf16 As[128 * 64];
    __shared__ bf16 Bs[128 * 64];
    const int m0 = blockIdx.y * 128;
    const int n0 = blockIdx.x * 128;
    f32x4 acc[4][4] = {};
    gemm_core(A, Bt, 1536, m0, n0, As, Bs, acc);

    const int tid  = threadIdx.x;
    const int wave = tid >> 6;
    const int lane = tid & 63;
    const int quad = lane >> 4;
    const int l15  = lane & 15;
    const int wm   = (wave >> 1) * 64;
    const int wn   = (wave & 1) * 64;
    const int odd  = l15 & 1;

#pragma unroll
    for (int j = 0; j < 4; ++j) {
        const int col = n0 + wn + j * 16 + l15;
        const float bv = bias[col];
        const float freq = exp2f(-(float)((col & 127) >> 1) * INVF_C);
#pragma unroll
        for (int i = 0; i < 4; ++i) {
            const int rowb = m0 + wm + i * 16 + quad * 4;
#pragma unroll
            for (int r = 0; r < 4; ++r) {
                const int row = rowb + r;
                const float v = acc[i][j][r] + bv;
                qC[(size_t)row * 2048 + col] = (bf16)(v * 0.0625f);
                const float vp = __shfl_xor(v, 1, 64);
                const float x1 = odd ? vp : v;
                const float x2 = odd ? v  : vp;
                const float ang = (float)(row & 2047) * freq;
                float sn, cs;
                __sincosf(ang, &sn, &cs);
                const float res = odd ? (x1 * sn + x2 * cs) : (x1 * cs - x2 * sn);
                qR[(size_t)row * 2048 + col] = (bf16)(res * 0.0625f);
            }
        }
    }
}

// vC (B*S, H*128) bf16 -> vT (B*H, 128, S). grid (S/32, 128/32, 32), block (32,8)
__global__ void transpose_v(const bf16* __restrict__ vC, bf16* __restrict__ vT)
{
    __shared__ bf16 tile[32][33];
    const int bh = blockIdx.z, b = bh >> 4, h = bh & 15;
    const int s0 = blockIdx.x * 32, d0 = blockIdx.y * 32;
    const int tx = threadIdx.x, ty = threadIdx.y;
    for (int i = ty; i < 32; i += 8)
        tile[i][tx] = vC[((size_t)(b * 2048 + s0 + i)) * 2048 + h * 128 + d0 + tx];
    __syncthreads();
    for (int i = ty; i < 32; i += 8)
        vT[((size_t)(bh * 128 + d0 + i)) * 2048 + s0 + tx] = tile[tx][i];
}

// ---------------------------------------------------------------------------
// per-head interleaved RoPE (kR path), layout (B*S, H*128), fp32 input.
// __sincosf: no scratch slow path (round-3 post-mortem).
// ---------------------------------------------------------------------------
__global__ void rope_heads_f(const float* __restrict__ in, bf16* __restrict__ out)
{
    const int idx = blockIdx.x * 256 + threadIdx.x;     // 2*2048*16*64 total
    const int j = idx & 63;
    const int h = (idx >> 6) & 15;
    const int s = (idx >> 10) & 2047;
    const int b = idx >> 21;
    const size_t src = ((size_t)(b * 2048 + s)) * 2048 + h * 128 + 2 * j;
    const float x1 = in[src], x2 = in[src + 1];
    const float ang = (float)s * exp2f(-(float)j * INVF_C);
    float sn, cs;
    __sincosf(ang, &sn, &cs);
    out[src]     = (bf16)(x1 * cs - x2 * sn);
    out[src + 1] = (bf16)(x1 * sn + x2 * cs);
}

// ---------------------------------------------------------------------------
// Flash attention, causal. Split operands, all bf16:
//   qC,qR (PRE-SCALED by 2^-4), kC,kR : (B*S, H*128);  Vt : (B*H, 128, S).
// BQ=128 (8 waves x 16 q-rows, wave-local softmax), BKV=64.
// Grid (bh=32, y=16): 512 blocks, 2/CU -> all co-resident.
// Balance remap: co-resident pair (y, y+8) -> q-tiles (2y, 15-2y) -> constant
// 34 KV-tile-units per CU (verified round 2: 159 -> 138 us).
// launch_bounds(512,2): 2 blocks/CU; (512,4) spilled (round-1 post-mortem).
// No setprio / no defer-max (regressed round 5; 8-wave lockstep = m190 null).
// No split-wave symmetric tiles (round-9: +44% staging iterations, 174 us).
// T14 async-stage verified round 6 (134 -> 127 us, VGPR 84, no spill).
// Round-11 (verified: VALU 28.7->25.0, 127.9->125.9 us): pre-scaled scores,
// wave-uniform diag branch.
// LDS: Ks 64x264 + Vs 128x72 + Ps 128x72 = 70656 B.
// ---------------------------------------------------------------------------
__global__ __launch_bounds__(512, 2)
void mla_attn(const bf16* __restrict__ qCp, const bf16* __restrict__ qRp,
              const bf16* __restrict__ kCp, const bf16* __restrict__ kRp,
              const bf16* __restrict__ Vt, bf16* __restrict__ ctx)
{
    __shared__ bf16 Ks[64 * 264];
    __shared__ bf16 Vs[128 * 72];
    __shared__ bf16 Ps[128 * 72];
    const int bh   = blockIdx.x;
    const int b    = bh >> 4, hh = bh & 15;
    const int yq   = blockIdx.y;
    const int qt   = (yq < 8) ? (2 * yq) : (31 - 2 * yq);   // balance remap
    const int q0   = qt * 128;
    const int tid  = threadIdx.x;
    const int wave = tid >> 6;
    const int lane = tid & 63;
    const int quad = lane >> 4;
    const int l15  = lane & 15;
    const int wq   = q0 + wave * 16;       // wave's first q row

    // Q fragments resident (A-operand: m=lane&15, k=quad*8+j).
    bf16x8 qf[8];
    {
        const size_t qoff = ((size_t)(b * 2048 + wq + l15)) * 2048
                          + hh * 128 + quad * 8;
#pragma unroll
        for (int ks = 0; ks < 4; ++ks) {
            qf[ks]     = *(const bf16x8*)(qCp + qoff + ks * 32);
            qf[4 + ks] = *(const bf16x8*)(qRp + qoff + ks * 32);
        }
    }

    float mstate[4], lstate[4];
    f32x4 o[8];
#pragma unroll
    for (int r = 0; r < 4; ++r) { mstate[r] = -1e30f; lstate[r] = 0.0f; }
#pragma unroll
    for (int dt = 0; dt < 8; ++dt) { f32x4 z = {0.f, 0.f, 0.f, 0.f}; o[dt] = z; }

    const int krow = tid >> 4, kcol = (tid & 15) * 8;   // K staging (512 thr)
    const int vsr  = tid >> 3, vsc  = (tid & 7) * 8;    // V staging

    // T14 staging registers (6 x bf16x8 = 24 VGPR)
    bf16x8 stKC[2], stKR[2], stV[2];

    const int ntiles = 2 * qt + 2;

    // prologue: load tile 0 into regs, write LDS, sync
    {
#pragma unroll
        for (int it = 0; it < 2; ++it) {
            const int row = it * 32 + krow;
            const size_t g = ((size_t)(b * 2048 + row)) * 2048 + hh * 128 + kcol;
            stKC[it] = *(const bf16x8*)(kCp + g);
            stKR[it] = *(const bf16x8*)(kRp + g);
        }
#pragma unroll
        for (int it = 0; it < 2; ++it) {
            const int d = it * 64 + vsr;
            stV[it] = *(const bf16x8*)(Vt + ((size_t)(bh * 128 + d)) * 2048 + vsc);
        }
#pragma unroll
        for (int it = 0; it < 2; ++it) {
            const int row = it * 32 + krow;
            *(bf16x8*)&Ks[row * 264 + kcol]       = stKC[it];
            *(bf16x8*)&Ks[row * 264 + 128 + kcol] = stKR[it];
        }
#pragma unroll
        for (int it = 0; it < 2; ++it) {
            const int d = it * 64 + vsr;
            *(bf16x8*)&Vs[d * 72 + vsc] = stV[it];
        }
    }
    __syncthreads();

    for (int t = 0; t < ntiles; ++t) {
        const int kk0 = t * 64;

        // T14: issue next tile's global loads; latency hides under compute(t)
        if (t + 1 < ntiles) {
            const int nk0 = kk0 + 64;
#pragma unroll
            for (int it = 0; it < 2; ++it) {
                const int row = it * 32 + krow;
                const size_t g = ((size_t)(b * 2048 + nk0 + row)) * 2048 + hh * 128 + kcol;
                stKC[it] = *(const bf16x8*)(kCp + g);
                stKR[it] = *(const bf16x8*)(kRp + g);
            }
#pragma unroll
            for (int it = 0; it < 2; ++it) {
                const int d = it * 64 + vsr;
                stV[it] = *(const bf16x8*)(Vt + ((size_t)(bh * 128 + d)) * 2048 + nk0 + vsc);
            }
        }

        if (kk0 <= wq + 15) {   // wave-uniform: tile not fully masked
            f32x4 sc[4] = {};
#pragma unroll
            for (int ks = 0; ks < 8; ++ks)
#pragma unroll
                for (int j = 0; j < 4; ++j) {
                    bf16x8 kf = *(const bf16x8*)&Ks[(j * 16 + l15) * 264 + ks * 32 + quad * 8];
                    sc[j] = __builtin_amdgcn_mfma_f32_16x16x32_bf16(qf[ks], kf, sc[j], 0, 0, 0);
                }

            // scores are pre-scaled (q carries 2^-4); only diag tiles mask.
            const bool diag = (kk0 + 63 > wq);   // wave-uniform branch
            float rowmax[4] = {-1e30f, -1e30f, -1e30f, -1e30f};
            if (diag) {
#pragma unroll
                for (int j = 0; j < 4; ++j) {
                    const int kkcol = kk0 + j * 16 + l15;
#pragma unroll
                    for (int r = 0; r < 4; ++r) {
                        float s = sc[j][r];
                        if (kkcol > wq + quad * 4 + r) s = -1e30f;
                        sc[j][r] = s;
                        rowmax[r] = fmaxf(rowmax[r], s);
                    }
                }
            } else {
#pragma unroll
                for (int j = 0; j < 4; ++j)
#pragma unroll
                    for (int r = 0; r < 4; ++r)
                        rowmax[r] = fmaxf(rowmax[r], sc[j][r]);
            }
#pragma unroll
            for (int r = 0; r < 4; ++r) {  // reduce across the 16 col-lanes
                float v = rowmax[r];
                v = fmaxf(v, __shfl_xor(v, 1, 64));
                v = fmaxf(v, __shfl_xor(v, 2, 64));
                v = fmaxf(v, __shfl_xor(v, 4, 64));
                v = fmaxf(v, __shfl_xor(v, 8, 64));
                rowmax[r] = v;
            }
            float alpha[4];
#pragma unroll
            for (int r = 0; r < 4; ++r) {
                const float mnew = fmaxf(mstate[r], rowmax[r]);
                alpha[r] = __expf(mstate[r] - mnew);
                mstate[r] = mnew;
            }
            float rowsum[4] = {0.f, 0.f, 0.f, 0.f};
#pragma unroll
            for (int j = 0; j < 4; ++j)
#pragma unroll
                for (int r = 0; r < 4; ++r) {
                    const float p = __expf(sc[j][r] - mstate[r]);
                    sc[j][r] = p;
                    rowsum[r] += p;
                }
#pragma unroll
            for (int r = 0; r < 4; ++r) {
                float v = rowsum[r];
                v += __shfl_xor(v, 1, 64);
                v += __shfl_xor(v, 2, 64);
                v += __shfl_xor(v, 4, 64);
                v += __shfl_xor(v, 8, 64);
                lstate[r] = lstate[r] * alpha[r] + v;
            }
            // P: C-layout -> LDS -> A-operand layout (verified, m120)
#pragma unroll
            for (int j = 0; j < 4; ++j)
#pragma unroll
                for (int r = 0; r < 4; ++r)
                    Ps[(wave * 16 + quad * 4 + r) * 72 + j * 16 + l15] = (bf16)sc[j][r];
#pragma unroll
            for (int dt = 0; dt < 8; ++dt)
#pragma unroll
                for (int r = 0; r < 4; ++r)
                    o[dt][r] *= alpha[r];
#pragma unroll
            for (int ks2 = 0; ks2 < 2; ++ks2) {
                bf16x8 pf = *(const bf16x8*)&Ps[(wave * 16 + l15) * 72 + ks2 * 32 + quad * 8];
#pragma unroll
                for (int dt = 0; dt < 8; ++dt) {
                    bf16x8 vf = *(const bf16x8*)&Vs[(dt * 16 + l15) * 72 + ks2 * 32 + quad * 8];
                    o[dt] = __builtin_amdgcn_mfma_f32_16x16x32_bf16(pf, vf, o[dt], 0, 0, 0);
                }
            }
        }

        __syncthreads();   // everyone done reading Ks/Vs of tile t
        if (t + 1 < ntiles) {
            // T14: LDS write of the prefetched tile (vmcnt drained on use)
#pragma unroll
            for (int it = 0; it < 2; ++it) {
                const int row = it * 32 + krow;
                *(bf16x8*)&Ks[row * 264 + kcol]       = stKC[it];
                *(bf16x8*)&Ks[row * 264 + 128 + kcol] = stKR[it];
            }
#pragma unroll
            for (int it = 0; it < 2; ++it) {
                const int d = it * 64 + vsr;
                *(bf16x8*)&Vs[d * 72 + vsc] = stV[it];
            }
        }
        __syncthreads();   // staged data visible for tile t+1
    }

    float inv_l[4];
#pragma unroll
    for (int r = 0; r < 4; ++r) inv_l[r] = 1.0f / lstate[r];
#pragma unroll
    for (int dt = 0; dt < 8; ++dt) {
        const int d = dt * 16 + l15;
#pragma unroll
        for (int r = 0; r < 4; ++r) {
            const int q = wq + quad * 4 + r;
            ctx[((size_t)(b * 2048 + q)) * 2048 + hh * 128 + d] = (bf16)(o[dt][r] * inv_l[r]);
        }
    }
}

// ---------------------------------------------------------------------------
extern "C" void kernel_launch(void* const* d_in, const int* in_sizes, int n_in,
                              void* d_out, int out_size, void* d_ws, size_t ws_size,
                              hipStream_t stream)
{
    const float* h     = (const float*)d_in[0];
    const float* W_DKV = (const float*)d_in[1];
    const float* b_DKV = (const float*)d_in[2];
    const float* W_UK  = (const float*)d_in[3];
    const float* b_UK  = (const float*)d_in[4];
    const float* W_UV  = (const float*)d_in[5];
    const float* b_UV  = (const float*)d_in[6];
    const float* W_DQ  = (const float*)d_in[7];
    const float* b_DQ  = (const float*)d_in[8];
    const float* W_UQ  = (const float*)d_in[9];
    const float* b_UQ  = (const float*)d_in[10];
    const float* W_KR  = (const float*)d_in[11];
    const float* b_KR  = (const float*)d_in[12];
    const float* W_O   = (const float*)d_in[13];
    const float* b_O   = (const float*)d_in[14];

    float* out   = (float*)d_out;             // (4096, 2048)  output 0, fp32
    float* cKV_f = out + (size_t)8388608;     // (4096, 512)   output 1
    float* krc_f = out + (size_t)10485760;    // (4096, 2048)  output 2

    // out-proper (33.5 MB) is dead until the final GEMM -> park qC + qR
    // there; both consumed by mla_attn before the final GEMM overwrites.
    bf16* qC = (bf16*)d_out;                  // (B*S, H*128)
    bf16* qR = (bf16*)d_out + 8388608;        // (B*S, H*128)

    // ws (bf16 elements), lifetimes:
    //  hb    @0        8.4M  cast -> batch1; then reused as kR
    //  cKVb  @8.4M     2.1M  batch1 -> batch45
    //  cQ    @10.5M    6.3M  batch1 -> gemm_q
    //  WtAll @16.8M    8.4M  tc -> b1; tc -> b45; tcUQ -> q; then vT; tcWO
    //  kC    @25.2M    8.4M  batch45 -> attn
    //  vC    @33.6M    8.4M  batch45 -> transpose_v; then ctx (attn -> final)
    bf16* ws    = (bf16*)d_ws;
    bf16* hb    = ws + 0;
    bf16* cKVb  = ws + 8388608;
    bf16* cQ    = ws + 10485760;
    bf16* WtAll = ws + 16777216;
    bf16* kC    = ws + 25165824;
    bf16* vC    = ws + 33554432;
    bf16* kR    = hb;              // hb dead after batch1
    bf16* vT    = WtAll;           // WtAll free between gemm_q and tc(WO)
    bf16* ctx   = vC;              // vC dead after transpose_v

    dim3 tb(32, 8);

    cast_to_bf16<<<8192, 256, 0, stream>>>(h, hb, 8388608);

    // WtAll rows: [0,512)=W_DKV^T, [512,2560)=W_KR^T, [2560,4096)=W_DQ^T
    transpose_cast<<<dim3(8, 32),  256, 0, stream>>>(W_DKV, WtAll,           2048, 512);
    transpose_cast<<<dim3(32, 32), 256, 0, stream>>>(W_KR,  WtAll + 1048576, 2048, 2048);
    transpose_cast<<<dim3(24, 32), 256, 0, stream>>>(W_DQ,  WtAll + 5242880, 2048, 1536);

    gemm_batch1<<<dim3(32, 32), 256, 0, stream>>>(hb, WtAll, b_DKV, b_KR, b_DQ,
                                                  cKV_f, cKVb, krc_f, cQ);
    // hb dead from here
    rope_heads_f<<<16384, 256, 0, stream>>>(krc_f, kR);

    // Wt45 rows: [0,2048)=W_UK^T, [2048,4096)=W_UV^T (K=512)
    transpose_cast<<<dim3(32, 8), 256, 0, stream>>>(W_UK, WtAll,           512, 2048);
    transpose_cast<<<dim3(32, 8), 256, 0, stream>>>(W_UV, WtAll + 1048576, 512, 2048);
    gemm_batch45<<<dim3(32, 32), 256, 0, stream>>>(cKVb, WtAll, b_UK, b_UV, kC, vC);

    transpose_cast<<<dim3(32, 24), 256, 0, stream>>>(W_UQ, WtAll, 1536, 2048);
    gemm_q_rope<<<dim3(16, 32), 256, 0, stream>>>(cQ, WtAll, b_UQ, qC, qR);

    transpose_v<<<dim3(64, 4, 32), tb, 0, stream>>>(vC, vT);   // vC consumed

    mla_attn<<<dim3(32, 16), 512, 0, stream>>>(qC, qR, kC, kR, vT, ctx);

    transpose_cast<<<dim3(32, 32), 256, 0, stream>>>(W_O, WtAll, 2048, 2048);
    gemm_bt<<<dim3(16, 32), 256, 0, stream>>>(ctx, WtAll, b_O, out, nullptr, 4096, 2048, 2048);
}

// Round 13
// 519.880 us; speedup vs baseline: 1.1138x; 1.0062x over previous
//
#include <hip/hip_runtime.h>
#include <cstdint>
#include <cstddef>

typedef __bf16 bf16;
typedef __bf16 bf16x2 __attribute__((ext_vector_type(2)));
typedef __bf16 bf16x8 __attribute__((ext_vector_type(8)));
typedef float  f32x4  __attribute__((ext_vector_type(4)));

#define INVF_C 0.20762050593046014f   // log2(10000)/64

// global -> LDS async copy, 16B per lane. LDS base must be wave-uniform;
// HW scatters lane i at base + 16*i. (m97-verified pattern.)
__device__ __forceinline__ void async_copy16(const void* g, void* l)
{
    auto gp = (__attribute__((address_space(1))) const void*)(reinterpret_cast<uintptr_t>(g));
    auto lp = (__attribute__((address_space(3))) void*)(uint32_t)(reinterpret_cast<uintptr_t>(l));
    __builtin_amdgcn_global_load_lds(gp, lp, 16, 0, 0);
}

// ---------------------------------------------------------------------------
// elementwise fp32 -> bf16 cast, 4 elems/thread, n % 4 == 0
// ---------------------------------------------------------------------------
__global__ void cast_to_bf16(const float* __restrict__ in, bf16* __restrict__ out, int n)
{
    const int i = (blockIdx.x * 256 + threadIdx.x) * 4;
    if (i < n) {
        const float4 v = *(const float4*)(in + i);
        out[i]     = (bf16)v.x;
        out[i + 1] = (bf16)v.y;
        out[i + 2] = (bf16)v.z;
        out[i + 3] = (bf16)v.w;
    }
}

// ---------------------------------------------------------------------------
// fused transpose + cast: out[c*R + r] = (bf16)in[r*C + c]; in is RxC fp32.
// 64x64 tile, 256 threads, float4 loads + bf16x2 stores (verified round 12:
// 536.3 -> 523.1 us isolated). R, C multiples of 64. grid (C/64, R/64).
// ---------------------------------------------------------------------------
__global__ __launch_bounds__(256)
void transpose_cast(const float* __restrict__ in, bf16* __restrict__ out,
                    int R, int Ccols)
{
    __shared__ float tile[64][65];
    const int c0 = blockIdx.x * 64;
    const int r0 = blockIdx.y * 64;
    const int tid = threadIdx.x;
    const int lr = tid >> 4;
    const int lc = (tid & 15) * 4;
#pragma unroll
    for (int i = 0; i < 4; ++i) {
        const int row = i * 16 + lr;
        const float4 v = *(const float4*)(in + (size_t)(r0 + row) * Ccols + c0 + lc);
        tile[row][lc]     = v.x;
        tile[row][lc + 1] = v.y;
        tile[row][lc + 2] = v.z;
        tile[row][lc + 3] = v.w;
    }
    __syncthreads();
    const int rr  = (tid & 31) * 2;
    const int cc0 = tid >> 5;
#pragma unroll
    for (int i = 0; i < 8; ++i) {
        const int cc = i * 8 + cc0;
        bf16x2 p = { (bf16)tile[rr][cc], (bf16)tile[rr + 1][cc] };
        *(bf16x2*)(out + (size_t)(c0 + cc) * R + r0 + rr) = p;
    }
}

// ---------------------------------------------------------------------------
// Shared GEMM main loop (m97 structure): 128x128 tile, BK=64, 4 waves 2x2,
// global_load_lds width-16 staging into unpadded LDS. Verified rounds 0-12.
// No XCD swizzle: operands are L3-resident (round-5 regression; m160).
// ---------------------------------------------------------------------------
__device__ __forceinline__ void gemm_core(const bf16* __restrict__ A,
                                          const bf16* __restrict__ Bt,
                                          int K, int m0, int n0,
                                          bf16* As, bf16* Bs,
                                          f32x4 (&acc)[4][4])
{
    const int tid  = threadIdx.x;
    const int wave = tid >> 6;
    const int lane = tid & 63;
    const int quad = lane >> 4;
    const int l15  = lane & 15;
    const int wm   = (wave >> 1) * 64;
    const int wn   = (wave & 1) * 64;

    // staging: wave w covers rows [w*32, w*32+32) in 4 issues of 8 rows;
    // lane l -> row l>>3, col chunk (l&7)*8 (matches lane*16B LDS scatter)
    const int srow = lane >> 3;
    const int scol = (lane & 7) * 8;
    const bf16* Ab = A  + (size_t)(m0 + wave * 32 + srow) * K + scol;
    const bf16* Bb = Bt + (size_t)(n0 + wave * 32 + srow) * K + scol;
    bf16* AsW = &As[(wave * 32) * 64];
    bf16* BsW = &Bs[(wave * 32) * 64];

    for (int k0 = 0; k0 < K; k0 += 64) {
        __syncthreads();   // previous tile fully consumed
#pragma unroll
        for (int i = 0; i < 4; ++i) {
            async_copy16(Ab + (size_t)(i * 8) * K + k0, AsW + i * 8 * 64);
            async_copy16(Bb + (size_t)(i * 8) * K + k0, BsW + i * 8 * 64);
        }
        __syncthreads();   // drains vmcnt(0) -> staged data visible
#pragma unroll
        for (int ks = 0; ks < 2; ++ks) {
            bf16x8 af[4], bfr[4];
#pragma unroll
            for (int i = 0; i < 4; ++i)
                af[i] = *(const bf16x8*)&As[(wm + i * 16 + l15) * 64 + ks * 32 + quad * 8];
#pragma unroll
            for (int j = 0; j < 4; ++j)
                bfr[j] = *(const bf16x8*)&Bs[(wn + j * 16 + l15) * 64 + ks * 32 + quad * 8];
#pragma unroll
            for (int i = 0; i < 4; ++i)
#pragma unroll
                for (int j = 0; j < 4; ++j)
                    acc[i][j] = __builtin_amdgcn_mfma_f32_16x16x32_bf16(af[i], bfr[j], acc[i][j], 0, 0, 0);
        }
    }
}

// ---------------------------------------------------------------------------
// Generic C[M,N] = A @ Bt^T + bias; dual fp32/bf16 epilogue (final GEMM).
// ---------------------------------------------------------------------------
__global__ __launch_bounds__(256, 2)
void gemm_bt(const bf16* __restrict__ A, const bf16* __restrict__ Bt,
             const float* __restrict__ bias, float* __restrict__ C,
             bf16* __restrict__ Cb, int M, int N, int K)
{
    __shared__ bf16 As[128 * 64];
    __shared__ bf16 Bs[128 * 64];
    const int m0 = blockIdx.y * 128;
    const int n0 = blockIdx.x * 128;
    f32x4 acc[4][4] = {};
    gemm_core(A, Bt, K, m0, n0, As, Bs, acc);

    const int tid  = threadIdx.x;
    const int wave = tid >> 6;
    const int lane = tid & 63;
    const int quad = lane >> 4;
    const int l15  = lane & 15;
    const int wm   = (wave >> 1) * 64;
    const int wn   = (wave & 1) * 64;

    // C/D layout: col = lane&15, row = quad*4 + r (verified m89/m91)
#pragma unroll
    for (int j = 0; j < 4; ++j) {
        const int col = n0 + wn + j * 16 + l15;
        const float bv = bias[col];
#pragma unroll
        for (int i = 0; i < 4; ++i) {
            const int row = m0 + wm + i * 16 + quad * 4;
#pragma unroll
            for (int r = 0; r < 4; ++r) {
                const float v = acc[i][j][r] + bv;
                if (C)  C [(size_t)(row + r) * N + col] = v;
                if (Cb) Cb[(size_t)(row + r) * N + col] = (bf16)v;
            }
        }
    }
}

// ---------------------------------------------------------------------------
// Batched GEMM #1: A=hb (4096x2048), B = [W_DKV^T | W_KR^T | W_DQ^T]
// stacked as WtAll (4096 x 2048). N=4096 -> 1024 blocks (full device).
// Section epilogues: cols [0,512) -> cKV fp32+bf16; [512,2560) -> krc fp32;
// [2560,4096) -> cQ bf16. Section boundaries are multiples of 128.
// ---------------------------------------------------------------------------
__global__ __launch_bounds__(256, 2)
void gemm_batch1(const bf16* __restrict__ A, const bf16* __restrict__ WtAll,
                 const float* __restrict__ bDKV, const float* __restrict__ bKR,
                 const float* __restrict__ bDQ,
                 float* __restrict__ cKV_f, bf16* __restrict__ cKVb,
                 float* __restrict__ krc_f, bf16* __restrict__ cQ)
{
    __shared__ bf16 As[128 * 64];
    __shared__ bf16 Bs[128 * 64];
    const int m0 = blockIdx.y * 128;
    const int n0 = blockIdx.x * 128;
    f32x4 acc[4][4] = {};
    gemm_core(A, WtAll, 2048, m0, n0, As, Bs, acc);

    const int tid  = threadIdx.x;
    const int wave = tid >> 6;
    const int lane = tid & 63;
    const int quad = lane >> 4;
    const int l15  = lane & 15;
    const int wm   = (wave >> 1) * 64;
    const int wn   = (wave & 1) * 64;

    if (n0 < 512) {
#pragma unroll
        for (int j = 0; j < 4; ++j) {
            const int col = n0 + wn + j * 16 + l15;
            const float bv = bDKV[col];
#pragma unroll
            for (int i = 0; i < 4; ++i) {
                const int row = m0 + wm + i * 16 + quad * 4;
#pragma unroll
                for (int r = 0; r < 4; ++r) {
                    const float v = acc[i][j][r] + bv;
                    cKV_f[(size_t)(row + r) * 512 + col] = v;
                    cKVb [(size_t)(row + r) * 512 + col] = (bf16)v;
                }
            }
        }
    } else if (n0 < 2560) {
#pragma unroll
        for (int j = 0; j < 4; ++j) {
            const int col = n0 + wn + j * 16 + l15;
            const int cl  = col - 512;
            const float bv = bKR[cl];
#pragma unroll
            for (int i = 0; i < 4; ++i) {
                const int row = m0 + wm + i * 16 + quad * 4;
#pragma unroll
                for (int r = 0; r < 4; ++r)
                    krc_f[(size_t)(row + r) * 2048 + cl] = acc[i][j][r] + bv;
            }
        }
    } else {
#pragma unroll
        for (int j = 0; j < 4; ++j) {
            const int col = n0 + wn + j * 16 + l15;
            const int cl  = col - 2560;
            const float bv = bDQ[cl];
#pragma unroll
            for (int i = 0; i < 4; ++i) {
                const int row = m0 + wm + i * 16 + quad * 4;
#pragma unroll
                for (int r = 0; r < 4; ++r)
                    cQ[(size_t)(row + r) * 1536 + cl] = (bf16)(acc[i][j][r] + bv);
            }
        }
    }
}

// ---------------------------------------------------------------------------
// Batched GEMM #4+5: A=cKVb (4096x512), B = [W_UK^T | W_UV^T] (4096x512).
// Cols [0,2048) -> kC; [2048,4096) -> vC. Both bf16.
// ---------------------------------------------------------------------------
__global__ __launch_bounds__(256, 2)
void gemm_batch45(const bf16* __restrict__ A, const bf16* __restrict__ Wt45,
                  const float* __restrict__ bUK, const float* __restrict__ bUV,
                  bf16* __restrict__ kC, bf16* __restrict__ vC)
{
    __shared__ bf16 As[128 * 64];
    __shared__ bf16 Bs[128 * 64];
    const int m0 = blockIdx.y * 128;
    const int n0 = blockIdx.x * 128;
    f32x4 acc[4][4] = {};
    gemm_core(A, Wt45, 512, m0, n0, As, Bs, acc);

    const int tid  = threadIdx.x;
    const int wave = tid >> 6;
    const int lane = tid & 63;
    const int quad = lane >> 4;
    const int l15  = lane & 15;
    const int wm   = (wave >> 1) * 64;
    const int wn   = (wave & 1) * 64;

    const bool isK = (n0 < 2048);
    bf16* outp = isK ? kC : vC;
    const float* bp = isK ? bUK : bUV;
    const int base = isK ? 0 : 2048;
#pragma unroll
    for (int j = 0; j < 4; ++j) {
        const int col = n0 + wn + j * 16 + l15;
        const int cl  = col - base;
        const float bv = bp[cl];
#pragma unroll
        for (int i = 0; i < 4; ++i) {
            const int row = m0 + wm + i * 16 + quad * 4;
#pragma unroll
            for (int r = 0; r < 4; ++r)
                outp[(size_t)(row + r) * 2048 + cl] = (bf16)(acc[i][j][r] + bv);
        }
    }
}

// ---------------------------------------------------------------------------
// qC GEMM with fused RoPE epilogue: writes qC = (A@Wt+b)*2^-4 (bf16) AND
// qR = rope(A@Wt+b)*2^-4 (bf16). PRE-SCALED by 1/sqrt(256) = 0.0625 (round
// 11): power-of-2 scale is exact in bf16 (exponent shift), rope is linear
// so scale commutes, and MFMA over uniformly 2^-4-scaled operands is
// bit-identical to scaling the scores afterward -> attn drops 16 v_mul/tile.
// __sincosf (hw v_sin/v_cos): sincosf's Payne-Hanek slow path used scratch
// -> 845 MB WRITE_SIZE (round-3 post-mortem). Angle err ~2e-4 rad << bf16.
// ---------------------------------------------------------------------------
__global__ __launch_bounds__(256, 2)
void gemm_q_rope(const bf16* __restrict__ A, const bf16* __restrict__ Bt,
                 const float* __restrict__ bias,
                 bf16* __restrict__ qC, bf16* __restrict__ qR)
{
    __shared__ bf16 As[128 * 64];
    __shared__ bf16 Bs[128 * 64];
    const int m0 = blockIdx.y * 128;
    const int n0 = blockIdx.x * 128;
    f32x4 acc[4][4] = {};
    gemm_core(A, Bt, 1536, m0, n0, As, Bs, acc);

    const int tid  = threadIdx.x;
    const int wave = tid >> 6;
    const int lane = tid & 63;
    const int quad = lane >> 4;
    const int l15  = lane & 15;
    const int wm   = (wave >> 1) * 64;
    const int wn   = (wave & 1) * 64;
    const int odd  = l15 & 1;

#pragma unroll
    for (int j = 0; j < 4; ++j) {
        const int col = n0 + wn + j * 16 + l15;
        const float bv = bias[col];
        const float freq = exp2f(-(float)((col & 127) >> 1) * INVF_C);
#pragma unroll
        for (int i = 0; i < 4; ++i) {
            const int rowb = m0 + wm + i * 16 + quad * 4;
#pragma unroll
            for (int r = 0; r < 4; ++r) {
                const int row = rowb + r;
                const float v = acc[i][j][r] + bv;
                qC[(size_t)row * 2048 + col] = (bf16)(v * 0.0625f);
                const float vp = __shfl_xor(v, 1, 64);
                const float x1 = odd ? vp : v;
                const float x2 = odd ? v  : vp;
                const float ang = (float)(row & 2047) * freq;
                float sn, cs;
                __sincosf(ang, &sn, &cs);
                const float res = odd ? (x1 * sn + x2 * cs) : (x1 * cs - x2 * sn);
                qR[(size_t)row * 2048 + col] = (bf16)(res * 0.0625f);
            }
        }
    }
}

// ---------------------------------------------------------------------------
// vC (B*S, H*128) bf16 -> vT (B*H, 128, S). Round-13 vectorized: 64x64 tile,
// bf16x8 global loads (16B/lane), scalar-transposed LDS writes into [64][72]
// (144B rows = 16B-aligned; per-instr bank coverage uniform), bf16x8 LDS
// reads + 16B/lane coalesced stores. Global transactions 8x fewer than the
// scalar 32x33 version. grid (S/64, 128/64, 32), block 256.
// ---------------------------------------------------------------------------
__global__ __launch_bounds__(256)
void transpose_v(const bf16* __restrict__ vC, bf16* __restrict__ vT)
{
    __shared__ bf16 tile[64][72];   // [d][s]
    const int bh = blockIdx.z, b = bh >> 4, h = bh & 15;
    const int s0 = blockIdx.x * 64, d0 = blockIdx.y * 64;
    const int tid = threadIdx.x;
#pragma unroll
    for (int it = 0; it < 2; ++it) {
        const int idx = it * 256 + tid;
        const int s  = idx >> 3;            // 0..63
        const int dc = (idx & 7) * 8;       // 0..56
        bf16x8 v = *(const bf16x8*)(vC + ((size_t)(b * 2048 + s0 + s)) * 2048
                                       + h * 128 + d0 + dc);
#pragma unroll
        for (int e = 0; e < 8; ++e)
            tile[dc + e][s] = v[e];
    }
    __syncthreads();
#pragma unroll
    for (int it = 0; it < 2; ++it) {
        const int idx = it * 256 + tid;
        const int d  = idx >> 3;
        const int sc = (idx & 7) * 8;
        *(bf16x8*)(vT + ((size_t)(bh * 128 + d0 + d)) * 2048 + s0 + sc) =
            *(const bf16x8*)&tile[d][sc];
    }
}

// ---------------------------------------------------------------------------
// per-head interleaved RoPE (kR path), layout (B*S, H*128), fp32 input.
// Round-13 vectorized: 8 elems (4 pairs)/thread, 2x float4 loads + one
// bf16x8 store. Same trig count; 8x wider transactions.
// __sincosf: no scratch slow path (round-3 post-mortem).
// ---------------------------------------------------------------------------
__global__ void rope_heads_f(const float* __restrict__ in, bf16* __restrict__ out)
{
    const int idx = blockIdx.x * 256 + threadIdx.x;   // 2*2048*16*16 total
    const int t = idx & 15;              // 8-elem chunk within 128-elem head
    const int h = (idx >> 4) & 15;
    const int s = (idx >> 8) & 2047;
    const int b = idx >> 19;
    const size_t src = ((size_t)(b * 2048 + s)) * 2048 + h * 128 + t * 8;
    const float4 va = *(const float4*)(in + src);
    const float4 vb = *(const float4*)(in + src + 4);
    const float x[8] = {va.x, va.y, va.z, va.w, vb.x, vb.y, vb.z, vb.w};
    bf16x8 o;
#pragma unroll
    for (int p = 0; p < 4; ++p) {
        const int j = t * 4 + p;
        const float ang = (float)s * exp2f(-(float)j * INVF_C);
        float sn, cs;
        __sincosf(ang, &sn, &cs);
        o[2 * p]     = (bf16)(x[2 * p] * cs - x[2 * p + 1] * sn);
        o[2 * p + 1] = (bf16)(x[2 * p] * sn + x[2 * p + 1] * cs);
    }
    *(bf16x8*)(out + src) = o;
}

// ---------------------------------------------------------------------------
// Flash attention, causal. Split operands, all bf16:
//   qC,qR (PRE-SCALED by 2^-4), kC,kR : (B*S, H*128);  Vt : (B*H, 128, S).
// BQ=128 (8 waves x 16 q-rows, wave-local softmax), BKV=64.
// Grid (bh=32, y=16): 512 blocks, 2/CU -> all co-resident.
// Balance remap: co-resident pair (y, y+8) -> q-tiles (2y, 15-2y) -> constant
// 34 KV-tile-units per CU (verified round 2: 159 -> 138 us).
// launch_bounds(512,2): 2 blocks/CU; (512,4) spilled (round-1 post-mortem).
// No setprio / no defer-max (regressed round 5; 8-wave lockstep = m190 null).
// No split-wave symmetric tiles (round-9: +44% staging iterations, 174 us).
// T14 async-stage verified round 6 (134 -> 127 us, VGPR 84, no spill).
// Round-11 (verified: VALU 28.7->25.0, 127.9->125.9 us): pre-scaled scores,
// wave-uniform diag branch.
// LDS: Ks 64x264 + Vs 128x72 + Ps 128x72 = 70656 B.
// ---------------------------------------------------------------------------
__global__ __launch_bounds__(512, 2)
void mla_attn(const bf16* __restrict__ qCp, const bf16* __restrict__ qRp,
              const bf16* __restrict__ kCp, const bf16* __restrict__ kRp,
              const bf16* __restrict__ Vt, bf16* __restrict__ ctx)
{
    __shared__ bf16 Ks[64 * 264];
    __shared__ bf16 Vs[128 * 72];
    __shared__ bf16 Ps[128 * 72];
    const int bh   = blockIdx.x;
    const int b    = bh >> 4, hh = bh & 15;
    const int yq   = blockIdx.y;
    const int qt   = (yq < 8) ? (2 * yq) : (31 - 2 * yq);   // balance remap
    const int q0   = qt * 128;
    const int tid  = threadIdx.x;
    const int wave = tid >> 6;
    const int lane = tid & 63;
    const int quad = lane >> 4;
    const int l15  = lane & 15;
    const int wq   = q0 + wave * 16;       // wave's first q row

    // Q fragments resident (A-operand: m=lane&15, k=quad*8+j).
    bf16x8 qf[8];
    {
        const size_t qoff = ((size_t)(b * 2048 + wq + l15)) * 2048
                          + hh * 128 + quad * 8;
#pragma unroll
        for (int ks = 0; ks < 4; ++ks) {
            qf[ks]     = *(const bf16x8*)(qCp + qoff + ks * 32);
            qf[4 + ks] = *(const bf16x8*)(qRp + qoff + ks * 32);
        }
    }

    float mstate[4], lstate[4];
    f32x4 o[8];
#pragma unroll
    for (int r = 0; r < 4; ++r) { mstate[r] = -1e30f; lstate[r] = 0.0f; }
#pragma unroll
    for (int dt = 0; dt < 8; ++dt) { f32x4 z = {0.f, 0.f, 0.f, 0.f}; o[dt] = z; }

    const int krow = tid >> 4, kcol = (tid & 15) * 8;   // K staging (512 thr)
    const int vsr  = tid >> 3, vsc  = (tid & 7) * 8;    // V staging

    // T14 staging registers (6 x bf16x8 = 24 VGPR)
    bf16x8 stKC[2], stKR[2], stV[2];

    const int ntiles = 2 * qt + 2;

    // prologue: load tile 0 into regs, write LDS, sync
    {
#pragma unroll
        for (int it = 0; it < 2; ++it) {
            const int row = it * 32 + krow;
            const size_t g = ((size_t)(b * 2048 + row)) * 2048 + hh * 128 + kcol;
            stKC[it] = *(const bf16x8*)(kCp + g);
            stKR[it] = *(const bf16x8*)(kRp + g);
        }
#pragma unroll
        for (int it = 0; it < 2; ++it) {
            const int d = it * 64 + vsr;
            stV[it] = *(const bf16x8*)(Vt + ((size_t)(bh * 128 + d)) * 2048 + vsc);
        }
#pragma unroll
        for (int it = 0; it < 2; ++it) {
            const int row = it * 32 + krow;
            *(bf16x8*)&Ks[row * 264 + kcol]       = stKC[it];
            *(bf16x8*)&Ks[row * 264 + 128 + kcol] = stKR[it];
        }
#pragma unroll
        for (int it = 0; it < 2; ++it) {
            const int d = it * 64 + vsr;
            *(bf16x8*)&Vs[d * 72 + vsc] = stV[it];
        }
    }
    __syncthreads();

    for (int t = 0; t < ntiles; ++t) {
        const int kk0 = t * 64;

        // T14: issue next tile's global loads; latency hides under compute(t)
        if (t + 1 < ntiles) {
            const int nk0 = kk0 + 64;
#pragma unroll
            for (int it = 0; it < 2; ++it) {
                const int row = it * 32 + krow;
                const size_t g = ((size_t)(b * 2048 + nk0 + row)) * 2048 + hh * 128 + kcol;
                stKC[it] = *(const bf16x8*)(kCp + g);
                stKR[it] = *(const bf16x8*)(kRp + g);
            }
#pragma unroll
            for (int it = 0; it < 2; ++it) {
                const int d = it * 64 + vsr;
                stV[it] = *(const bf16x8*)(Vt + ((size_t)(bh * 128 + d)) * 2048 + nk0 + vsc);
            }
        }

        if (kk0 <= wq + 15) {   // wave-uniform: tile not fully masked
            f32x4 sc[4] = {};
#pragma unroll
            for (int ks = 0; ks < 8; ++ks)
#pragma unroll
                for (int j = 0; j < 4; ++j) {
                    bf16x8 kf = *(const bf16x8*)&Ks[(j * 16 + l15) * 264 + ks * 32 + quad * 8];
                    sc[j] = __builtin_amdgcn_mfma_f32_16x16x32_bf16(qf[ks], kf, sc[j], 0, 0, 0);
                }

            // scores are pre-scaled (q carries 2^-4); only diag tiles mask.
            const bool diag = (kk0 + 63 > wq);   // wave-uniform branch
            float rowmax[4] = {-1e30f, -1e30f, -1e30f, -1e30f};
            if (diag) {
#pragma unroll
                for (int j = 0; j < 4; ++j) {
                    const int kkcol = kk0 + j * 16 + l15;
#pragma unroll
                    for (int r = 0; r < 4; ++r) {
                        float s = sc[j][r];
                        if (kkcol > wq + quad * 4 + r) s = -1e30f;
                        sc[j][r] = s;
                        rowmax[r] = fmaxf(rowmax[r], s);
                    }
                }
            } else {
#pragma unroll
                for (int j = 0; j < 4; ++j)
#pragma unroll
                    for (int r = 0; r < 4; ++r)
                        rowmax[r] = fmaxf(rowmax[r], sc[j][r]);
            }
#pragma unroll
            for (int r = 0; r < 4; ++r) {  // reduce across the 16 col-lanes
                float v = rowmax[r];
                v = fmaxf(v, __shfl_xor(v, 1, 64));
                v = fmaxf(v, __shfl_xor(v, 2, 64));
                v = fmaxf(v, __shfl_xor(v, 4, 64));
                v = fmaxf(v, __shfl_xor(v, 8, 64));
                rowmax[r] = v;
            }
            float alpha[4];
#pragma unroll
            for (int r = 0; r < 4; ++r) {
                const float mnew = fmaxf(mstate[r], rowmax[r]);
                alpha[r] = __expf(mstate[r] - mnew);
                mstate[r] = mnew;
            }
            float rowsum[4] = {0.f, 0.f, 0.f, 0.f};
#pragma unroll
            for (int j = 0; j < 4; ++j)
#pragma unroll
                for (int r = 0; r < 4; ++r) {
                    const float p = __expf(sc[j][r] - mstate[r]);
                    sc[j][r] = p;
                    rowsum[r] += p;
                }
#pragma unroll
            for (int r = 0; r < 4; ++r) {
                float v = rowsum[r];
                v += __shfl_xor(v, 1, 64);
                v += __shfl_xor(v, 2, 64);
                v += __shfl_xor(v, 4, 64);
                v += __shfl_xor(v, 8, 64);
                lstate[r] = lstate[r] * alpha[r] + v;
            }
            // P: C-layout -> LDS -> A-operand layout (verified, m120)
#pragma unroll
            for (int j = 0; j < 4; ++j)
#pragma unroll
                for (int r = 0; r < 4; ++r)
                    Ps[(wave * 16 + quad * 4 + r) * 72 + j * 16 + l15] = (bf16)sc[j][r];
#pragma unroll
            for (int dt = 0; dt < 8; ++dt)
#pragma unroll
                for (int r = 0; r < 4; ++r)
                    o[dt][r] *= alpha[r];
#pragma unroll
            for (int ks2 = 0; ks2 < 2; ++ks2) {
                bf16x8 pf = *(const bf16x8*)&Ps[(wave * 16 + l15) * 72 + ks2 * 32 + quad * 8];
#pragma unroll
                for (int dt = 0; dt < 8; ++dt) {
                    bf16x8 vf = *(const bf16x8*)&Vs[(dt * 16 + l15) * 72 + ks2 * 32 + quad * 8];
                    o[dt] = __builtin_amdgcn_mfma_f32_16x16x32_bf16(pf, vf, o[dt], 0, 0, 0);
                }
            }
        }

        __syncthreads();   // everyone done reading Ks/Vs of tile t
        if (t + 1 < ntiles) {
            // T14: LDS write of the prefetched tile (vmcnt drained on use)
#pragma unroll
            for (int it = 0; it < 2; ++it) {
                const int row = it * 32 + krow;
                *(bf16x8*)&Ks[row * 264 + kcol]       = stKC[it];
                *(bf16x8*)&Ks[row * 264 + 128 + kcol] = stKR[it];
            }
#pragma unroll
            for (int it = 0; it < 2; ++it) {
                const int d = it * 64 + vsr;
                *(bf16x8*)&Vs[d * 72 + vsc] = stV[it];
            }
        }
        __syncthreads();   // staged data visible for tile t+1
    }

    float inv_l[4];
#pragma unroll
    for (int r = 0; r < 4; ++r) inv_l[r] = 1.0f / lstate[r];
#pragma unroll
    for (int dt = 0; dt < 8; ++dt) {
        const int d = dt * 16 + l15;
#pragma unroll
        for (int r = 0; r < 4; ++r) {
            const int q = wq + quad * 4 + r;
            ctx[((size_t)(b * 2048 + q)) * 2048 + hh * 128 + d] = (bf16)(o[dt][r] * inv_l[r]);
        }
    }
}

// ---------------------------------------------------------------------------
extern "C" void kernel_launch(void* const* d_in, const int* in_sizes, int n_in,
                              void* d_out, int out_size, void* d_ws, size_t ws_size,
                              hipStream_t stream)
{
    const float* h     = (const float*)d_in[0];
    const float* W_DKV = (const float*)d_in[1];
    const float* b_DKV = (const float*)d_in[2];
    const float* W_UK  = (const float*)d_in[3];
    const float* b_UK  = (const float*)d_in[4];
    const float* W_UV  = (const float*)d_in[5];
    const float* b_UV  = (const float*)d_in[6];
    const float* W_DQ  = (const float*)d_in[7];
    const float* b_DQ  = (const float*)d_in[8];
    const float* W_UQ  = (const float*)d_in[9];
    const float* b_UQ  = (const float*)d_in[10];
    const float* W_KR  = (const float*)d_in[11];
    const float* b_KR  = (const float*)d_in[12];
    const float* W_O   = (const float*)d_in[13];
    const float* b_O   = (const float*)d_in[14];

    float* out   = (float*)d_out;             // (4096, 2048)  output 0, fp32
    float* cKV_f = out + (size_t)8388608;     // (4096, 512)   output 1
    float* krc_f = out + (size_t)10485760;    // (4096, 2048)  output 2

    // out-proper (33.5 MB) is dead until the final GEMM -> park qC + qR
    // there; both consumed by mla_attn before the final GEMM overwrites.
    bf16* qC = (bf16*)d_out;                  // (B*S, H*128)
    bf16* qR = (bf16*)d_out + 8388608;        // (B*S, H*128)

    // ws (bf16 elements), lifetimes:
    //  hb    @0        8.4M  cast -> batch1; then reused as kR
    //  cKVb  @8.4M     2.1M  batch1 -> batch45
    //  cQ    @10.5M    6.3M  batch1 -> gemm_q
    //  WtAll @16.8M    8.4M  tc -> b1; tc -> b45; tcUQ -> q; then vT; tcWO
    //  kC    @25.2M    8.4M  batch45 -> attn
    //  vC    @33.6M    8.4M  batch45 -> transpose_v; then ctx (attn -> final)
    bf16* ws    = (bf16*)d_ws;
    bf16* hb    = ws + 0;
    bf16* cKVb  = ws + 8388608;
    bf16* cQ    = ws + 10485760;
    bf16* WtAll = ws + 16777216;
    bf16* kC    = ws + 25165824;
    bf16* vC    = ws + 33554432;
    bf16* kR    = hb;              // hb dead after batch1
    bf16* vT    = WtAll;           // WtAll free between gemm_q and tc(WO)
    bf16* ctx   = vC;              // vC dead after transpose_v

    cast_to_bf16<<<8192, 256, 0, stream>>>(h, hb, 8388608);

    // WtAll rows: [0,512)=W_DKV^T, [512,2560)=W_KR^T, [2560,4096)=W_DQ^T
    transpose_cast<<<dim3(8, 32),  256, 0, stream>>>(W_DKV, WtAll,           2048, 512);
    transpose_cast<<<dim3(32, 32), 256, 0, stream>>>(W_KR,  WtAll + 1048576, 2048, 2048);
    transpose_cast<<<dim3(24, 32), 256, 0, stream>>>(W_DQ,  WtAll + 5242880, 2048, 1536);

    gemm_batch1<<<dim3(32, 32), 256, 0, stream>>>(hb, WtAll, b_DKV, b_KR, b_DQ,
                                                  cKV_f, cKVb, krc_f, cQ);
    // hb dead from here
    rope_heads_f<<<4096, 256, 0, stream>>>(krc_f, kR);

    // Wt45 rows: [0,2048)=W_UK^T, [2048,4096)=W_UV^T (K=512)
    transpose_cast<<<dim3(32, 8), 256, 0, stream>>>(W_UK, WtAll,           512, 2048);
    transpose_cast<<<dim3(32, 8), 256, 0, stream>>>(W_UV, WtAll + 1048576, 512, 2048);
    gemm_batch45<<<dim3(32, 32), 256, 0, stream>>>(cKVb, WtAll, b_UK, b_UV, kC, vC);

    transpose_cast<<<dim3(32, 24), 256, 0, stream>>>(W_UQ, WtAll, 1536, 2048);
    gemm_q_rope<<<dim3(16, 32), 256, 0, stream>>>(cQ, WtAll, b_UQ, qC, qR);

    transpose_v<<<dim3(32, 2, 32), 256, 0, stream>>>(vC, vT);   // vC consumed

    mla_attn<<<dim3(32, 16), 512, 0, stream>>>(qC, qR, kC, kR, vT, ctx);

    transpose_cast<<<dim3(32, 32), 256, 0, stream>>>(W_O, WtAll, 2048, 2048);
    gemm_bt<<<dim3(16, 32), 256, 0, stream>>>(ctx, WtAll, b_O, out, nullptr, 4096, 2048, 2048);
}

// Round 14
// 511.796 us; speedup vs baseline: 1.1314x; 1.0158x over previous
//
#include <hip/hip_runtime.h>
#include <cstdint>
#include <cstddef>

typedef __bf16 bf16;
typedef __bf16 bf16x2 __attribute__((ext_vector_type(2)));
typedef __bf16 bf16x8 __attribute__((ext_vector_type(8)));
typedef float  f32x4  __attribute__((ext_vector_type(4)));

#define INVF_C 0.20762050593046014f   // log2(10000)/64

// global -> LDS async copy, 16B per lane. LDS base must be wave-uniform;
// HW scatters lane i at base + 16*i. (m97-verified pattern.)
__device__ __forceinline__ void async_copy16(const void* g, void* l)
{
    auto gp = (__attribute__((address_space(1))) const void*)(reinterpret_cast<uintptr_t>(g));
    auto lp = (__attribute__((address_space(3))) void*)(uint32_t)(reinterpret_cast<uintptr_t>(l));
    __builtin_amdgcn_global_load_lds(gp, lp, 16, 0, 0);
}

// ---------------------------------------------------------------------------
// elementwise fp32 -> bf16 cast, 4 elems/thread, n % 4 == 0
// ---------------------------------------------------------------------------
__global__ void cast_to_bf16(const float* __restrict__ in, bf16* __restrict__ out, int n)
{
    const int i = (blockIdx.x * 256 + threadIdx.x) * 4;
    if (i < n) {
        const float4 v = *(const float4*)(in + i);
        out[i]     = (bf16)v.x;
        out[i + 1] = (bf16)v.y;
        out[i + 2] = (bf16)v.z;
        out[i + 3] = (bf16)v.w;
    }
}

// ---------------------------------------------------------------------------
// 64x64 transpose+cast tile body (verified rounds 12-13): float4 loads,
// bf16x2 stores. in is RxC fp32 (C=Cc), out col-major panel at outBase with
// row stride Rstride: out[(c)*Rstride + r].
// ---------------------------------------------------------------------------
__device__ __forceinline__ void tc_tile(const float* __restrict__ in, int Cc,
                                        bf16* __restrict__ out, int Rstride,
                                        int r0, int cl0, int cg0, int tid)
{
    __shared__ float tile[64][65];
    const int lr = tid >> 4;
    const int lc = (tid & 15) * 4;
#pragma unroll
    for (int i = 0; i < 4; ++i) {
        const int row = i * 16 + lr;
        const float4 v = *(const float4*)(in + (size_t)(r0 + row) * Cc + cl0 + lc);
        tile[row][lc]     = v.x;
        tile[row][lc + 1] = v.y;
        tile[row][lc + 2] = v.z;
        tile[row][lc + 3] = v.w;
    }
    __syncthreads();
    const int rr  = (tid & 31) * 2;
    const int cc0 = tid >> 5;
#pragma unroll
    for (int i = 0; i < 8; ++i) {
        const int cc = i * 8 + cc0;
        bf16x2 p = { (bf16)tile[rr][cc], (bf16)tile[rr + 1][cc] };
        *(bf16x2*)(out + (size_t)(cg0 + cc) * Rstride + r0 + rr) = p;
    }
}

// generic single-weight version (used for UQ, WO)
__global__ __launch_bounds__(256)
void transpose_cast(const float* __restrict__ in, bf16* __restrict__ out,
                    int R, int Ccols)
{
    tc_tile(in, Ccols, out, R, blockIdx.y * 64, blockIdx.x * 64,
            blockIdx.x * 64, threadIdx.x);
}

// merged DKV|KR|DQ -> WtAll (4096 x 2048). grid (64, 32). Sections by
// global col: [0,512)=W_DKV(2048x512), [512,2560)=W_KR(2048x2048),
// [2560,4096)=W_DQ(2048x1536); boundaries are multiples of 64 ->
// block-uniform select. (merge logic verified rounds 7-8, body rounds 12-13)
__global__ __launch_bounds__(256)
void transpose_cast3(const float* __restrict__ w0, const float* __restrict__ w1,
                     const float* __restrict__ w2, bf16* __restrict__ outAll)
{
    const int cg0 = blockIdx.x * 64;
    const float* in; int cl0, Cc;
    if (cg0 < 512)       { in = w0; cl0 = cg0;        Cc = 512;  }
    else if (cg0 < 2560) { in = w1; cl0 = cg0 - 512;  Cc = 2048; }
    else                 { in = w2; cl0 = cg0 - 2560; Cc = 1536; }
    tc_tile(in, Cc, outAll, 2048, blockIdx.y * 64, cl0, cg0, threadIdx.x);
}

// merged UK|UV -> Wt45 (4096 x 512), both inputs (512, 2048). grid (64, 8).
__global__ __launch_bounds__(256)
void transpose_cast2(const float* __restrict__ w0, const float* __restrict__ w1,
                     bf16* __restrict__ outAll)
{
    const int cg0 = blockIdx.x * 64;
    const float* in = (cg0 < 2048) ? w0 : w1;
    const int cl0 = cg0 & 2047;
    tc_tile(in, 2048, outAll, 512, blockIdx.y * 64, cl0, cg0, threadIdx.x);
}

// ---------------------------------------------------------------------------
// Shared GEMM main loop (m97 structure): 128x128 tile, BK=64, 4 waves 2x2,
// global_load_lds width-16 staging into unpadded LDS. Verified rounds 0-13.
// No XCD swizzle: operands are L3-resident (round-5 regression; m160).
// ---------------------------------------------------------------------------
__device__ __forceinline__ void gemm_core(const bf16* __restrict__ A,
                                          const bf16* __restrict__ Bt,
                                          int K, int m0, int n0,
                                          bf16* As, bf16* Bs,
                                          f32x4 (&acc)[4][4])
{
    const int tid  = threadIdx.x;
    const int wave = tid >> 6;
    const int lane = tid & 63;
    const int quad = lane >> 4;
    const int l15  = lane & 15;
    const int wm   = (wave >> 1) * 64;
    const int wn   = (wave & 1) * 64;

    const int srow = lane >> 3;
    const int scol = (lane & 7) * 8;
    const bf16* Ab = A  + (size_t)(m0 + wave * 32 + srow) * K + scol;
    const bf16* Bb = Bt + (size_t)(n0 + wave * 32 + srow) * K + scol;
    bf16* AsW = &As[(wave * 32) * 64];
    bf16* BsW = &Bs[(wave * 32) * 64];

    for (int k0 = 0; k0 < K; k0 += 64) {
        __syncthreads();   // previous tile fully consumed
#pragma unroll
        for (int i = 0; i < 4; ++i) {
            async_copy16(Ab + (size_t)(i * 8) * K + k0, AsW + i * 8 * 64);
            async_copy16(Bb + (size_t)(i * 8) * K + k0, BsW + i * 8 * 64);
        }
        __syncthreads();   // drains vmcnt(0) -> staged data visible
#pragma unroll
        for (int ks = 0; ks < 2; ++ks) {
            bf16x8 af[4], bfr[4];
#pragma unroll
            for (int i = 0; i < 4; ++i)
                af[i] = *(const bf16x8*)&As[(wm + i * 16 + l15) * 64 + ks * 32 + quad * 8];
#pragma unroll
            for (int j = 0; j < 4; ++j)
                bfr[j] = *(const bf16x8*)&Bs[(wn + j * 16 + l15) * 64 + ks * 32 + quad * 8];
#pragma unroll
            for (int i = 0; i < 4; ++i)
#pragma unroll
                for (int j = 0; j < 4; ++j)
                    acc[i][j] = __builtin_amdgcn_mfma_f32_16x16x32_bf16(af[i], bfr[j], acc[i][j], 0, 0, 0);
        }
    }
}

// ---------------------------------------------------------------------------
// Generic C[M,N] = A @ Bt^T + bias; dual fp32/bf16 epilogue (final GEMM).
// ---------------------------------------------------------------------------
__global__ __launch_bounds__(256, 2)
void gemm_bt(const bf16* __restrict__ A, const bf16* __restrict__ Bt,
             const float* __restrict__ bias, float* __restrict__ C,
             bf16* __restrict__ Cb, int M, int N, int K)
{
    __shared__ bf16 As[128 * 64];
    __shared__ bf16 Bs[128 * 64];
    const int m0 = blockIdx.y * 128;
    const int n0 = blockIdx.x * 128;
    f32x4 acc[4][4] = {};
    gemm_core(A, Bt, K, m0, n0, As, Bs, acc);

    const int tid  = threadIdx.x;
    const int wave = tid >> 6;
    const int lane = tid & 63;
    const int quad = lane >> 4;
    const int l15  = lane & 15;
    const int wm   = (wave >> 1) * 64;
    const int wn   = (wave & 1) * 64;

    // C/D layout: col = lane&15, row = quad*4 + r (verified m89/m91)
#pragma unroll
    for (int j = 0; j < 4; ++j) {
        const int col = n0 + wn + j * 16 + l15;
        const float bv = bias[col];
#pragma unroll
        for (int i = 0; i < 4; ++i) {
            const int row = m0 + wm + i * 16 + quad * 4;
#pragma unroll
            for (int r = 0; r < 4; ++r) {
                const float v = acc[i][j][r] + bv;
                if (C)  C [(size_t)(row + r) * N + col] = v;
                if (Cb) Cb[(size_t)(row + r) * N + col] = (bf16)v;
            }
        }
    }
}

// ---------------------------------------------------------------------------
// Batched GEMM #1: A=hb (4096x2048), B = [W_DKV^T | W_KR^T | W_DQ^T]
// stacked as WtAll (4096 x 2048). N=4096 -> 1024 blocks (full device).
// Section epilogues: cols [0,512) -> cKV fp32+bf16; [512,2560) -> krc fp32;
// [2560,4096) -> cQ bf16. Section boundaries are multiples of 128.
// ---------------------------------------------------------------------------
__global__ __launch_bounds__(256, 2)
void gemm_batch1(const bf16* __restrict__ A, const bf16* __restrict__ WtAll,
                 const float* __restrict__ bDKV, const float* __restrict__ bKR,
                 const float* __restrict__ bDQ,
                 float* __restrict__ cKV_f, bf16* __restrict__ cKVb,
                 float* __restrict__ krc_f, bf16* __restrict__ cQ)
{
    __shared__ bf16 As[128 * 64];
    __shared__ bf16 Bs[128 * 64];
    const int m0 = blockIdx.y * 128;
    const int n0 = blockIdx.x * 128;
    f32x4 acc[4][4] = {};
    gemm_core(A, WtAll, 2048, m0, n0, As, Bs, acc);

    const int tid  = threadIdx.x;
    const int wave = tid >> 6;
    const int lane = tid & 63;
    const int quad = lane >> 4;
    const int l15  = lane & 15;
    const int wm   = (wave >> 1) * 64;
    const int wn   = (wave & 1) * 64;

    if (n0 < 512) {
#pragma unroll
        for (int j = 0; j < 4; ++j) {
            const int col = n0 + wn + j * 16 + l15;
            const float bv = bDKV[col];
#pragma unroll
            for (int i = 0; i < 4; ++i) {
                const int row = m0 + wm + i * 16 + quad * 4;
#pragma unroll
                for (int r = 0; r < 4; ++r) {
                    const float v = acc[i][j][r] + bv;
                    cKV_f[(size_t)(row + r) * 512 + col] = v;
                    cKVb [(size_t)(row + r) * 512 + col] = (bf16)v;
                }
            }
        }
    } else if (n0 < 2560) {
#pragma unroll
        for (int j = 0; j < 4; ++j) {
            const int col = n0 + wn + j * 16 + l15;
            const int cl  = col - 512;
            const float bv = bKR[cl];
#pragma unroll
            for (int i = 0; i < 4; ++i) {
                const int row = m0 + wm + i * 16 + quad * 4;
#pragma unroll
                for (int r = 0; r < 4; ++r)
                    krc_f[(size_t)(row + r) * 2048 + cl] = acc[i][j][r] + bv;
            }
        }
    } else {
#pragma unroll
        for (int j = 0; j < 4; ++j) {
            const int col = n0 + wn + j * 16 + l15;
            const int cl  = col - 2560;
            const float bv = bDQ[cl];
#pragma unroll
            for (int i = 0; i < 4; ++i) {
                const int row = m0 + wm + i * 16 + quad * 4;
#pragma unroll
                for (int r = 0; r < 4; ++r)
                    cQ[(size_t)(row + r) * 1536 + cl] = (bf16)(acc[i][j][r] + bv);
            }
        }
    }
}

// ---------------------------------------------------------------------------
// Batched GEMM #4+5: A=cKVb (4096x512), B = [W_UK^T | W_UV^T] (4096x512).
// Cols [0,2048) -> kC; [2048,4096) -> vC. Both bf16.
// ---------------------------------------------------------------------------
__global__ __launch_bounds__(256, 2)
void gemm_batch45(const bf16* __restrict__ A, const bf16* __restrict__ Wt45,
                  const float* __restrict__ bUK, const float* __restrict__ bUV,
                  bf16* __restrict__ kC, bf16* __restrict__ vC)
{
    __shared__ bf16 As[128 * 64];
    __shared__ bf16 Bs[128 * 64];
    const int m0 = blockIdx.y * 128;
    const int n0 = blockIdx.x * 128;
    f32x4 acc[4][4] = {};
    gemm_core(A, Wt45, 512, m0, n0, As, Bs, acc);

    const int tid  = threadIdx.x;
    const int wave = tid >> 6;
    const int lane = tid & 63;
    const int quad = lane >> 4;
    const int l15  = lane & 15;
    const int wm   = (wave >> 1) * 64;
    const int wn   = (wave & 1) * 64;

    const bool isK = (n0 < 2048);
    bf16* outp = isK ? kC : vC;
    const float* bp = isK ? bUK : bUV;
    const int base = isK ? 0 : 2048;
#pragma unroll
    for (int j = 0; j < 4; ++j) {
        const int col = n0 + wn + j * 16 + l15;
        const int cl  = col - base;
        const float bv = bp[cl];
#pragma unroll
        for (int i = 0; i < 4; ++i) {
            const int row = m0 + wm + i * 16 + quad * 4;
#pragma unroll
            for (int r = 0; r < 4; ++r)
                outp[(size_t)(row + r) * 2048 + cl] = (bf16)(acc[i][j][r] + bv);
        }
    }
}

// ---------------------------------------------------------------------------
// qC GEMM with fused RoPE epilogue: writes qC = (A@Wt+b)*2^-4 (bf16) AND
// qR = rope(A@Wt+b)*2^-4 (bf16). PRE-SCALED by 1/sqrt(256) = 0.0625 (round
// 11): power-of-2 scale is exact in bf16, rope is linear so scale commutes.
// __sincosf (hw v_sin/v_cos): sincosf's Payne-Hanek slow path used scratch
// -> 845 MB WRITE_SIZE (round-3 post-mortem). Angle err ~2e-4 rad << bf16.
// ---------------------------------------------------------------------------
__global__ __launch_bounds__(256, 2)
void gemm_q_rope(const bf16* __restrict__ A, const bf16* __restrict__ Bt,
                 const float* __restrict__ bias,
                 bf16* __restrict__ qC, bf16* __restrict__ qR)
{
    __shared__ bf16 As[128 * 64];
    __shared__ bf16 Bs[128 * 64];
    const int m0 = blockIdx.y * 128;
    const int n0 = blockIdx.x * 128;
    f32x4 acc[4][4] = {};
    gemm_core(A, Bt, 1536, m0, n0, As, Bs, acc);

    const int tid  = threadIdx.x;
    const int wave = tid >> 6;
    const int lane = tid & 63;
    const int quad = lane >> 4;
    const int l15  = lane & 15;
    const int wm   = (wave >> 1) * 64;
    const int wn   = (wave & 1) * 64;
    const int odd  = l15 & 1;

#pragma unroll
    for (int j = 0; j < 4; ++j) {
        const int col = n0 + wn + j * 16 + l15;
        const float bv = bias[col];
        const float freq = exp2f(-(float)((col & 127) >> 1) * INVF_C);
#pragma unroll
        for (int i = 0; i < 4; ++i) {
            const int rowb = m0 + wm + i * 16 + quad * 4;
#pragma unroll
            for (int r = 0; r < 4; ++r) {
                const int row = rowb + r;
                const float v = acc[i][j][r] + bv;
                qC[(size_t)row * 2048 + col] = (bf16)(v * 0.0625f);
                const float vp = __shfl_xor(v, 1, 64);
                const float x1 = odd ? vp : v;
                const float x2 = odd ? v  : vp;
                const float ang = (float)(row & 2047) * freq;
                float sn, cs;
                __sincosf(ang, &sn, &cs);
                const float res = odd ? (x1 * sn + x2 * cs) : (x1 * cs - x2 * sn);
                qR[(size_t)row * 2048 + col] = (bf16)(res * 0.0625f);
            }
        }
    }
}

// ---------------------------------------------------------------------------
// vC (B*S, H*128) bf16 -> vT (B*H, 128, S). 64x64 tile, bf16x8 global loads,
// scalar-transposed LDS writes ([64][72], 144B rows), bf16x8 coalesced out.
// grid (S/64, 128/64, 32), block 256. (verified round 13)
// ---------------------------------------------------------------------------
__global__ __launch_bounds__(256)
void transpose_v(const bf16* __restrict__ vC, bf16* __restrict__ vT)
{
    __shared__ bf16 tile[64][72];   // [d][s]
    const int bh = blockIdx.z, b = bh >> 4, h = bh & 15;
    const int s0 = blockIdx.x * 64, d0 = blockIdx.y * 64;
    const int tid = threadIdx.x;
#pragma unroll
    for (int it = 0; it < 2; ++it) {
        const int idx = it * 256 + tid;
        const int s  = idx >> 3;            // 0..63
        const int dc = (idx & 7) * 8;       // 0..56
        bf16x8 v = *(const bf16x8*)(vC + ((size_t)(b * 2048 + s0 + s)) * 2048
                                       + h * 128 + d0 + dc);
#pragma unroll
        for (int e = 0; e < 8; ++e)
            tile[dc + e][s] = v[e];
    }
    __syncthreads();
#pragma unroll
    for (int it = 0; it < 2; ++it) {
        const int idx = it * 256 + tid;
        const int d  = idx >> 3;
        const int sc = (idx & 7) * 8;
        *(bf16x8*)(vT + ((size_t)(bh * 128 + d0 + d)) * 2048 + s0 + sc) =
            *(const bf16x8*)&tile[d][sc];
    }
}

// ---------------------------------------------------------------------------
// per-head interleaved RoPE (kR path), layout (B*S, H*128), fp32 input.
// 8 elems (4 pairs)/thread, 2x float4 loads + one bf16x8 store (round 13).
// __sincosf: no scratch slow path (round-3 post-mortem).
// ---------------------------------------------------------------------------
__global__ void rope_heads_f(const float* __restrict__ in, bf16* __restrict__ out)
{
    const int idx = blockIdx.x * 256 + threadIdx.x;   // 2*2048*16*16 total
    const int t = idx & 15;              // 8-elem chunk within 128-elem head
    const int h = (idx >> 4) & 15;
    const int s = (idx >> 8) & 2047;
    const int b = idx >> 19;
    const size_t src = ((size_t)(b * 2048 + s)) * 2048 + h * 128 + t * 8;
    const float4 va = *(const float4*)(in + src);
    const float4 vb = *(const float4*)(in + src + 4);
    const float x[8] = {va.x, va.y, va.z, va.w, vb.x, vb.y, vb.z, vb.w};
    bf16x8 o;
#pragma unroll
    for (int p = 0; p < 4; ++p) {
        const int j = t * 4 + p;
        const float ang = (float)s * exp2f(-(float)j * INVF_C);
        float sn, cs;
        __sincosf(ang, &sn, &cs);
        o[2 * p]     = (bf16)(x[2 * p] * cs - x[2 * p + 1] * sn);
        o[2 * p + 1] = (bf16)(x[2 * p] * sn + x[2 * p + 1] * cs);
    }
    *(bf16x8*)(out + src) = o;
}

// ---------------------------------------------------------------------------
// Flash attention, causal. Split operands, all bf16:
//   qC,qR (PRE-SCALED by 2^-4), kC,kR : (B*S, H*128);  Vt : (B*H, 128, S).
// BQ=128 (8 waves x 16 q-rows, wave-local softmax), BKV=64.
// Grid (bh=32, y=16): 512 blocks, 2/CU -> all co-resident.
// Balance remap: co-resident pair (y, y+8) -> q-tiles (2y, 15-2y) -> constant
// 34 KV-tile-units per CU (verified round 2: 159 -> 138 us).
// launch_bounds(512,2): 2 blocks/CU; (512,4) spilled (round-1 post-mortem).
// No setprio / no defer-max (regressed round 5; 8-wave lockstep = m190 null).
// No split-wave symmetric tiles (round-9: +44% staging iterations, 174 us).
// T14 async-stage verified round 6 (134 -> 127 us, VGPR 84, no spill).
// Round-11 (verified: VALU 28.7->25.0): pre-scaled scores, uniform diag.
// LDS: Ks 64x264 + Vs 128x72 + Ps 128x72 = 70656 B.
// ---------------------------------------------------------------------------
__global__ __launch_bounds__(512, 2)
void mla_attn(const bf16* __restrict__ qCp, const bf16* __restrict__ qRp,
              const bf16* __restrict__ kCp, const bf16* __restrict__ kRp,
              const bf16* __restrict__ Vt, bf16* __restrict__ ctx)
{
    __shared__ bf16 Ks[64 * 264];
    __shared__ bf16 Vs[128 * 72];
    __shared__ bf16 Ps[128 * 72];
    const int bh   = blockIdx.x;
    const int b    = bh >> 4, hh = bh & 15;
    const int yq   = blockIdx.y;
    const int qt   = (yq < 8) ? (2 * yq) : (31 - 2 * yq);   // balance remap
    const int q0   = qt * 128;
    const int tid  = threadIdx.x;
    const int wave = tid >> 6;
    const int lane = tid & 63;
    const int quad = lane >> 4;
    const int l15  = lane & 15;
    const int wq   = q0 + wave * 16;       // wave's first q row

    // Q fragments resident (A-operand: m=lane&15, k=quad*8+j).
    bf16x8 qf[8];
    {
        const size_t qoff = ((size_t)(b * 2048 + wq + l15)) * 2048
                          + hh * 128 + quad * 8;
#pragma unroll
        for (int ks = 0; ks < 4; ++ks) {
            qf[ks]     = *(const bf16x8*)(qCp + qoff + ks * 32);
            qf[4 + ks] = *(const bf16x8*)(qRp + qoff + ks * 32);
        }
    }

    float mstate[4], lstate[4];
    f32x4 o[8];
#pragma unroll
    for (int r = 0; r < 4; ++r) { mstate[r] = -1e30f; lstate[r] = 0.0f; }
#pragma unroll
    for (int dt = 0; dt < 8; ++dt) { f32x4 z = {0.f, 0.f, 0.f, 0.f}; o[dt] = z; }

    const int krow = tid >> 4, kcol = (tid & 15) * 8;   // K staging (512 thr)
    const int vsr  = tid >> 3, vsc  = (tid & 7) * 8;    // V staging

    // T14 staging registers (6 x bf16x8 = 24 VGPR)
    bf16x8 stKC[2], stKR[2], stV[2];

    const int ntiles = 2 * qt + 2;

    // prologue: load tile 0 into regs, write LDS, sync
    {
#pragma unroll
        for (int it = 0; it < 2; ++it) {
            const int row = it * 32 + krow;
            const size_t g = ((size_t)(b * 2048 + row)) * 2048 + hh * 128 + kcol;
            stKC[it] = *(const bf16x8*)(kCp + g);
            stKR[it] = *(const bf16x8*)(kRp + g);
        }
#pragma unroll
        for (int it = 0; it < 2; ++it) {
            const int d = it * 64 + vsr;
            stV[it] = *(const bf16x8*)(Vt + ((size_t)(bh * 128 + d)) * 2048 + vsc);
        }
#pragma unroll
        for (int it = 0; it < 2; ++it) {
            const int row = it * 32 + krow;
            *(bf16x8*)&Ks[row * 264 + kcol]       = stKC[it];
            *(bf16x8*)&Ks[row * 264 + 128 + kcol] = stKR[it];
        }
#pragma unroll
        for (int it = 0; it < 2; ++it) {
            const int d = it * 64 + vsr;
            *(bf16x8*)&Vs[d * 72 + vsc] = stV[it];
        }
    }
    __syncthreads();

    for (int t = 0; t < ntiles; ++t) {
        const int kk0 = t * 64;

        // T14: issue next tile's global loads; latency hides under compute(t)
        if (t + 1 < ntiles) {
            const int nk0 = kk0 + 64;
#pragma unroll
            for (int it = 0; it < 2; ++it) {
                const int row = it * 32 + krow;
                const size_t g = ((size_t)(b * 2048 + nk0 + row)) * 2048 + hh * 128 + kcol;
                stKC[it] = *(const bf16x8*)(kCp + g);
                stKR[it] = *(const bf16x8*)(kRp + g);
            }
#pragma unroll
            for (int it = 0; it < 2; ++it) {
                const int d = it * 64 + vsr;
                stV[it] = *(const bf16x8*)(Vt + ((size_t)(bh * 128 + d)) * 2048 + nk0 + vsc);
            }
        }

        if (kk0 <= wq + 15) {   // wave-uniform: tile not fully masked
            f32x4 sc[4] = {};
#pragma unroll
            for (int ks = 0; ks < 8; ++ks)
#pragma unroll
                for (int j = 0; j < 4; ++j) {
                    bf16x8 kf = *(const bf16x8*)&Ks[(j * 16 + l15) * 264 + ks * 32 + quad * 8];
                    sc[j] = __builtin_amdgcn_mfma_f32_16x16x32_bf16(qf[ks], kf, sc[j], 0, 0, 0);
                }

            // scores are pre-scaled (q carries 2^-4); only diag tiles mask.
            const bool diag = (kk0 + 63 > wq);   // wave-uniform branch
            float rowmax[4] = {-1e30f, -1e30f, -1e30f, -1e30f};
            if (diag) {
#pragma unroll
                for (int j = 0; j < 4; ++j) {
                    const int kkcol = kk0 + j * 16 + l15;
#pragma unroll
                    for (int r = 0; r < 4; ++r) {
                        float s = sc[j][r];
                        if (kkcol > wq + quad * 4 + r) s = -1e30f;
                        sc[j][r] = s;
                        rowmax[r] = fmaxf(rowmax[r], s);
                    }
                }
            } else {
#pragma unroll
                for (int j = 0; j < 4; ++j)
#pragma unroll
                    for (int r = 0; r < 4; ++r)
                        rowmax[r] = fmaxf(rowmax[r], sc[j][r]);
            }
#pragma unroll
            for (int r = 0; r < 4; ++r) {  // reduce across the 16 col-lanes
                float v = rowmax[r];
                v = fmaxf(v, __shfl_xor(v, 1, 64));
                v = fmaxf(v, __shfl_xor(v, 2, 64));
                v = fmaxf(v, __shfl_xor(v, 4, 64));
                v = fmaxf(v, __shfl_xor(v, 8, 64));
                rowmax[r] = v;
            }
            float alpha[4];
#pragma unroll
            for (int r = 0; r < 4; ++r) {
                const float mnew = fmaxf(mstate[r], rowmax[r]);
                alpha[r] = __expf(mstate[r] - mnew);
                mstate[r] = mnew;
            }
            float rowsum[4] = {0.f, 0.f, 0.f, 0.f};
#pragma unroll
            for (int j = 0; j < 4; ++j)
#pragma unroll
                for (int r = 0; r < 4; ++r) {
                    const float p = __expf(sc[j][r] - mstate[r]);
                    sc[j][r] = p;
                    rowsum[r] += p;
                }
#pragma unroll
            for (int r = 0; r < 4; ++r) {
                float v = rowsum[r];
                v += __shfl_xor(v, 1, 64);
                v += __shfl_xor(v, 2, 64);
                v += __shfl_xor(v, 4, 64);
                v += __shfl_xor(v, 8, 64);
                lstate[r] = lstate[r] * alpha[r] + v;
            }
            // P: C-layout -> LDS -> A-operand layout (verified, m120)
#pragma unroll
            for (int j = 0; j < 4; ++j)
#pragma unroll
                for (int r = 0; r < 4; ++r)
                    Ps[(wave * 16 + quad * 4 + r) * 72 + j * 16 + l15] = (bf16)sc[j][r];
#pragma unroll
            for (int dt = 0; dt < 8; ++dt)
#pragma unroll
                for (int r = 0; r < 4; ++r)
                    o[dt][r] *= alpha[r];
#pragma unroll
            for (int ks2 = 0; ks2 < 2; ++ks2) {
                bf16x8 pf = *(const bf16x8*)&Ps[(wave * 16 + l15) * 72 + ks2 * 32 + quad * 8];
#pragma unroll
                for (int dt = 0; dt < 8; ++dt) {
                    bf16x8 vf = *(const bf16x8*)&Vs[(dt * 16 + l15) * 72 + ks2 * 32 + quad * 8];
                    o[dt] = __builtin_amdgcn_mfma_f32_16x16x32_bf16(pf, vf, o[dt], 0, 0, 0);
                }
            }
        }

        __syncthreads();   // everyone done reading Ks/Vs of tile t
        if (t + 1 < ntiles) {
            // T14: LDS write of the prefetched tile (vmcnt drained on use)
#pragma unroll
            for (int it = 0; it < 2; ++it) {
                const int row = it * 32 + krow;
                *(bf16x8*)&Ks[row * 264 + kcol]       = stKC[it];
                *(bf16x8*)&Ks[row * 264 + 128 + kcol] = stKR[it];
            }
#pragma unroll
            for (int it = 0; it < 2; ++it) {
                const int d = it * 64 + vsr;
                *(bf16x8*)&Vs[d * 72 + vsc] = stV[it];
            }
        }
        __syncthreads();   // staged data visible for tile t+1
    }

    float inv_l[4];
#pragma unroll
    for (int r = 0; r < 4; ++r) inv_l[r] = 1.0f / lstate[r];
#pragma unroll
    for (int dt = 0; dt < 8; ++dt) {
        const int d = dt * 16 + l15;
#pragma unroll
        for (int r = 0; r < 4; ++r) {
            const int q = wq + quad * 4 + r;
            ctx[((size_t)(b * 2048 + q)) * 2048 + hh * 128 + d] = (bf16)(o[dt][r] * inv_l[r]);
        }
    }
}

// ---------------------------------------------------------------------------
extern "C" void kernel_launch(void* const* d_in, const int* in_sizes, int n_in,
                              void* d_out, int out_size, void* d_ws, size_t ws_size,
                              hipStream_t stream)
{
    const float* h     = (const float*)d_in[0];
    const float* W_DKV = (const float*)d_in[1];
    const float* b_DKV = (const float*)d_in[2];
    const float* W_UK  = (const float*)d_in[3];
    const float* b_UK  = (const float*)d_in[4];
    const float* W_UV  = (const float*)d_in[5];
    const float* b_UV  = (const float*)d_in[6];
    const float* W_DQ  = (const float*)d_in[7];
    const float* b_DQ  = (const float*)d_in[8];
    const float* W_UQ  = (const float*)d_in[9];
    const float* b_UQ  = (const float*)d_in[10];
    const float* W_KR  = (const float*)d_in[11];
    const float* b_KR  = (const float*)d_in[12];
    const float* W_O   = (const float*)d_in[13];
    const float* b_O   = (const float*)d_in[14];

    float* out   = (float*)d_out;             // (4096, 2048)  output 0, fp32
    float* cKV_f = out + (size_t)8388608;     // (4096, 512)   output 1
    float* krc_f = out + (size_t)10485760;    // (4096, 2048)  output 2

    // out-proper (33.5 MB) is dead until the final GEMM -> park qC + qR
    // there; both consumed by mla_attn before the final GEMM overwrites.
    bf16* qC = (bf16*)d_out;                  // (B*S, H*128)
    bf16* qR = (bf16*)d_out + 8388608;        // (B*S, H*128)

    // ws (bf16 elements), lifetimes:
    //  hb    @0        8.4M  cast -> batch1; then reused as kR
    //  cKVb  @8.4M     2.1M  batch1 -> batch45
    //  cQ    @10.5M    6.3M  batch1 -> gemm_q
    //  WtAll @16.8M    8.4M  tc -> b1; tc -> b45; tcUQ -> q; then vT; tcWO
    //  kC    @25.2M    8.4M  batch45 -> attn
    //  vC    @33.6M    8.4M  batch45 -> transpose_v; then ctx (attn -> final)
    bf16* ws    = (bf16*)d_ws;
    bf16* hb    = ws + 0;
    bf16* cKVb  = ws + 8388608;
    bf16* cQ    = ws + 10485760;
    bf16* WtAll = ws + 16777216;
    bf16* kC    = ws + 25165824;
    bf16* vC    = ws + 33554432;
    bf16* kR    = hb;              // hb dead after batch1
    bf16* vT    = WtAll;           // WtAll free between gemm_q and tc(WO)
    bf16* ctx   = vC;              // vC dead after transpose_v

    cast_to_bf16<<<8192, 256, 0, stream>>>(h, hb, 8388608);

    // WtAll rows: [0,512)=W_DKV^T, [512,2560)=W_KR^T, [2560,4096)=W_DQ^T
    transpose_cast3<<<dim3(64, 32), 256, 0, stream>>>(W_DKV, W_KR, W_DQ, WtAll);

    gemm_batch1<<<dim3(32, 32), 256, 0, stream>>>(hb, WtAll, b_DKV, b_KR, b_DQ,
                                                  cKV_f, cKVb, krc_f, cQ);
    // hb dead from here
    rope_heads_f<<<4096, 256, 0, stream>>>(krc_f, kR);

    // Wt45 rows: [0,2048)=W_UK^T, [2048,4096)=W_UV^T (K=512)
    transpose_cast2<<<dim3(64, 8), 256, 0, stream>>>(W_UK, W_UV, WtAll);
    gemm_batch45<<<dim3(32, 32), 256, 0, stream>>>(cKVb, WtAll, b_UK, b_UV, kC, vC);

    transpose_cast<<<dim3(32, 24), 256, 0, stream>>>(W_UQ, WtAll, 1536, 2048);
    gemm_q_rope<<<dim3(16, 32), 256, 0, stream>>>(cQ, WtAll, b_UQ, qC, qR);

    transpose_v<<<dim3(32, 2, 32), 256, 0, stream>>>(vC, vT);   // vC consumed

    mla_attn<<<dim3(32, 16), 512, 0, stream>>>(qC, qR, kC, kR, vT, ctx);

    transpose_cast<<<dim3(32, 32), 256, 0, stream>>>(W_O, WtAll, 2048, 2048);
    gemm_bt<<<dim3(16, 32), 256, 0, stream>>>(ctx, WtAll, b_O, out, nullptr, 4096, 2048, 2048);
}